// Round 1
// baseline (547.924 us; speedup 1.0000x reference)
//
#include <hip/hip_runtime.h>

#define BATCH 8192
#define FEAT  4096
#define MID   512
#define EMB   256
#define KCODE 512

typedef _Float16 half8 __attribute__((ext_vector_type(8)));
typedef _Float16 half4v __attribute__((ext_vector_type(4)));
typedef float floatx4 __attribute__((ext_vector_type(4)));

// Power-of-2 scales; descaled exactly in epilogues/reduces.
#define SC_X    512.0f
#define SC_W    4096.0f
#define SC_H    512.0f
#define SC_ENC  4096.0f
#define SC_CODE 4096.0f
#define SC_EMB  4096.0f
#define SC_TM   512.0f
#define DS_G1   (1.0f / (SC_X   * SC_W))
#define DS_G2   (1.0f / (SC_H   * SC_W))
#define DS_D1   (1.0f / (SC_EMB * SC_W))
#define DS_D2   (1.0f / (SC_TM  * SC_W))

#define GLD16(gp, lp)                                                          \
    __builtin_amdgcn_global_load_lds(                                          \
        (const __attribute__((address_space(1))) void*)(gp),                   \
        (__attribute__((address_space(3))) void*)(lp), 16, 0, 0)

// ---------------------------------------------------------------------------
// Split-K m97-style MFMA GEMM. Tile 128x128, BK=32, 4 waves (2x2 of 64x64).
// C = A @ B^T (B pre-split/scaled f16 hi/lo, TRANSPOSED [N][K]).
// NT=3: hi*hi + hi*lo + lo*hi (fp32-equivalent). NT=1: hi only.
// AF32=1: A is fp32, split to scaled f16 hi/lo in-register during staging.
// AF32=0: A pre-split hi/lo, staged via global_load_lds (width 16).
// If partOut != null: raw fp32 accumulators to partOut[ks*M*N + ...] (no
// bias/descale). Else: final epilogue (descale, bias, relu, fp32 / hi-lo out).
// swz: 1-D grid, b -> {m_lo=b&7, ks, n, m_hi}; all n/k-peers of an M-stripe
// share b%8 (same XCD) for L2-shared A; gridM%8==0 required.
// ---------------------------------------------------------------------------
template<int NT, int AF32>
__global__ __launch_bounds__(256)
void gemm_sk(const float* __restrict__ Af32,
             const _Float16* __restrict__ Ahg, const _Float16* __restrict__ Alg,
             const _Float16* __restrict__ BTh, const _Float16* __restrict__ BTl,
             float aScale,
             float* __restrict__ partOut,
             const float* __restrict__ bias, float descale, int relu,
             float* __restrict__ outF, _Float16* __restrict__ outHi,
             _Float16* __restrict__ outLo, float outScale,
             int M, int N, int K, int lgK, int lgN, int swz)
{
    __shared__ _Float16 AhS[128 * 32];
    __shared__ _Float16 BhS[128 * 32];
    __shared__ _Float16 AlS[NT == 3 ? 128 * 32 : 8];
    __shared__ _Float16 BlS[NT == 3 ? 128 * 32 : 8];

    const int tid  = threadIdx.x;
    const int lane = tid & 63;
    const int wave = tid >> 6;
    const int wm = wave >> 1, wn = wave & 1;
    const int l15  = lane & 15;
    const int quad = lane >> 4;
    const int q8   = quad * 8;

    int bm, bn, ks;
    if (swz) {
        int b = blockIdx.x;
        int mlo = b & 7;
        ks = (b >> 3) & ((1 << lgK) - 1);
        bn = (b >> (3 + lgK)) & ((1 << lgN) - 1);
        bm = ((b >> (3 + lgK + lgN)) << 3) | mlo;
    } else { bm = blockIdx.y; bn = blockIdx.x; ks = 0; }
    const int row0 = bm * 128, col0 = bn * 128;
    const int Kslice = K >> lgK;
    const int k0 = ks * Kslice;

    // GLD16 staging coords (covers 64 rows per call; two calls = 128 rows)
    const int sr4 = tid >> 2;
    const int sc4 = (tid & 3) * 8;
    const size_t aB0 = (size_t)(row0 + sr4) * K + sc4;
    const size_t aB1 = (size_t)(row0 + 64 + sr4) * K + sc4;
    const size_t bB0 = (size_t)(col0 + sr4) * K + sc4;
    const size_t bB1 = (size_t)(col0 + 64 + sr4) * K + sc4;
    const int l0 = tid * 8, l1 = 2048 + tid * 8;

    // AF32 staging coords (one pass: 256 threads x 16 elems = 128x32)
    const int sr2 = tid >> 1;
    const int sk2 = (tid & 1) * 16;
    const size_t aOff2 = (size_t)(row0 + sr2) * K + sk2;
    const int lA = sr2 * 32 + sk2;

    floatx4 acc[4][4] = {};

    for (int kt = 0; kt < Kslice; kt += 32) {
        // --- B staging: always GLD16 ---
        GLD16(BTh + bB0 + k0 + kt, &BhS[l0]);
        GLD16(BTh + bB1 + k0 + kt, &BhS[l1]);
        if (NT == 3) {
            GLD16(BTl + bB0 + k0 + kt, &BlS[l0]);
            GLD16(BTl + bB1 + k0 + kt, &BlS[l1]);
        }
        // --- A staging ---
        if (AF32) {
            const float* p = Af32 + aOff2 + k0 + kt;
            float4 f0 = *(const float4*)(p);
            float4 f1 = *(const float4*)(p + 4);
            float4 f2 = *(const float4*)(p + 8);
            float4 f3 = *(const float4*)(p + 12);
            float fv[16] = {f0.x,f0.y,f0.z,f0.w, f1.x,f1.y,f1.z,f1.w,
                            f2.x,f2.y,f2.z,f2.w, f3.x,f3.y,f3.z,f3.w};
            half8 hv0, hv1, lv0, lv1;
            #pragma unroll
            for (int e = 0; e < 8; ++e) {
                float v = fv[e] * aScale;
                _Float16 h = (_Float16)v;
                hv0[e] = h; lv0[e] = (_Float16)(v - (float)h);
            }
            #pragma unroll
            for (int e = 0; e < 8; ++e) {
                float v = fv[8 + e] * aScale;
                _Float16 h = (_Float16)v;
                hv1[e] = h; lv1[e] = (_Float16)(v - (float)h);
            }
            *(half8*)&AhS[lA] = hv0; *(half8*)&AhS[lA + 8] = hv1;
            if (NT == 3) { *(half8*)&AlS[lA] = lv0; *(half8*)&AlS[lA + 8] = lv1; }
        } else {
            GLD16(Ahg + aB0 + k0 + kt, &AhS[l0]);
            GLD16(Ahg + aB1 + k0 + kt, &AhS[l1]);
            if (NT == 3) {
                GLD16(Alg + aB0 + k0 + kt, &AlS[l0]);
                GLD16(Alg + aB1 + k0 + kt, &AlS[l1]);
            }
        }
        __syncthreads();

        half8 ah[4], al4[4], bh[4], bl4[4];
        #pragma unroll
        for (int i = 0; i < 4; ++i) {
            int ra = (wm * 64 + i * 16 + l15) * 32 + q8;
            int rb = (wn * 64 + i * 16 + l15) * 32 + q8;
            ah[i] = *(const half8*)&AhS[ra];
            bh[i] = *(const half8*)&BhS[rb];
            if (NT == 3) {
                al4[i] = *(const half8*)&AlS[ra];
                bl4[i] = *(const half8*)&BlS[rb];
            }
        }
        #pragma unroll
        for (int i = 0; i < 4; ++i)
            #pragma unroll
            for (int j = 0; j < 4; ++j) {
                acc[i][j] = __builtin_amdgcn_mfma_f32_16x16x32_f16(ah[i], bh[j], acc[i][j], 0, 0, 0);
                if (NT == 3) {
                    acc[i][j] = __builtin_amdgcn_mfma_f32_16x16x32_f16(ah[i],  bl4[j], acc[i][j], 0, 0, 0);
                    acc[i][j] = __builtin_amdgcn_mfma_f32_16x16x32_f16(al4[i], bh[j],  acc[i][j], 0, 0, 0);
                }
            }
        __syncthreads();
    }

    // Epilogue. C/D layout: col = lane&15, row = quad*4 + reg (verified m89).
    if (partOut) {
        float* po = partOut + (size_t)ks * M * N;
        #pragma unroll
        for (int j = 0; j < 4; ++j) {
            int col = col0 + wn * 64 + j * 16 + l15;
            #pragma unroll
            for (int i = 0; i < 4; ++i)
                #pragma unroll
                for (int t = 0; t < 4; ++t) {
                    int r = row0 + wm * 64 + i * 16 + quad * 4 + t;
                    po[(size_t)r * N + col] = acc[i][j][t];
                }
        }
    } else {
        #pragma unroll
        for (int j = 0; j < 4; ++j) {
            int col = col0 + wn * 64 + j * 16 + l15;
            float bcol = bias ? bias[col] : 0.0f;
            #pragma unroll
            for (int i = 0; i < 4; ++i)
                #pragma unroll
                for (int t = 0; t < 4; ++t) {
                    int r = row0 + wm * 64 + i * 16 + quad * 4 + t;
                    float v = acc[i][j][t] * descale + bcol;
                    if (relu) v = fmaxf(v, 0.0f);
                    size_t o = (size_t)r * N + col;
                    if (outF) outF[o] = v;
                    if (outHi) {
                        float sv = v * outScale;
                        _Float16 h = (_Float16)sv;
                        outHi[o] = h;
                        outLo[o] = (_Float16)(sv - (float)h);
                    }
                }
        }
    }
}

// ---------------------------------------------------------------------------
// Streaming fp32 -> scaled f16 hi/lo split (exact pair representation).
// Replaces the per-tile in-register split that gemm_sk<NT,1> did redundantly
// per n-block: split once at HBM bandwidth, then gemm stages via GLD16.
// ---------------------------------------------------------------------------
__global__ __launch_bounds__(256)
void split_scale(const float* __restrict__ src, _Float16* __restrict__ hi,
                 _Float16* __restrict__ lo, float scale, int n8)
{
    int stride = gridDim.x * 256;
    for (int i = blockIdx.x * 256 + threadIdx.x; i < n8; i += stride) {
        const float4* s = (const float4*)src + (size_t)2 * i;
        float4 a = s[0], b = s[1];
        float f[8] = {a.x, a.y, a.z, a.w, b.x, b.y, b.z, b.w};
        half8 hv, lv;
        #pragma unroll
        for (int e = 0; e < 8; ++e) {
            float v = f[e] * scale;
            _Float16 h = (_Float16)v;
            hv[e] = h;
            lv[e] = (_Float16)(v - (float)h);
        }
        ((half8*)hi)[i] = hv;
        ((half8*)lo)[i] = lv;
    }
}

// ---------------------------------------------------------------------------
// Split-K reduce: out = relu( (sum_s part[s]) * descale + bias ), emitting
// fp32 and/or scaled f16 hi/lo. float4 per thread.
// ---------------------------------------------------------------------------
__global__ __launch_bounds__(256)
void reduce_sk(const float* __restrict__ part, int nSlice, int MN, int N,
               const float* __restrict__ bias, float descale, int relu,
               float* __restrict__ outF, _Float16* __restrict__ outHi,
               _Float16* __restrict__ outLo, float outScale)
{
    int i = blockIdx.x * 256 + threadIdx.x;
    if (i * 4 >= MN) return;
    float4 s = ((const float4*)part)[i];
    for (int sl = 1; sl < nSlice; ++sl) {
        float4 p = ((const float4*)(part + (size_t)sl * MN))[i];
        s.x += p.x; s.y += p.y; s.z += p.z; s.w += p.w;
    }
    int col = (i * 4) % N;
    float v[4] = {s.x, s.y, s.z, s.w};
    #pragma unroll
    for (int e = 0; e < 4; ++e) {
        float t = v[e] * descale + (bias ? bias[col + e] : 0.0f);
        if (relu) t = fmaxf(t, 0.0f);
        v[e] = t;
    }
    if (outF) ((float4*)outF)[i] = *(float4*)v;
    if (outHi) {
        half4v hv, lv;
        #pragma unroll
        for (int e = 0; e < 4; ++e) {
            float sv = v[e] * outScale;
            _Float16 h = (_Float16)sv;
            hv[e] = h;
            lv[e] = (_Float16)(sv - (float)h);
        }
        ((half4v*)outHi)[i] = hv;
        ((half4v*)outLo)[i] = lv;
    }
}

// ---------------------------------------------------------------------------
// Transpose fp32 [R][C] -> scaled f16 hi/lo [C][R]. 32x32 LDS tiles.
// ---------------------------------------------------------------------------
__global__ __launch_bounds__(256)
void transpose_split(const float* __restrict__ src, _Float16* __restrict__ hi,
                     _Float16* __restrict__ lo, float scale, int R, int C)
{
    __shared__ float t[32][33];
    int tx = threadIdx.x & 31, ty = threadIdx.x >> 5;
    int r0 = blockIdx.y * 32, c0 = blockIdx.x * 32;
    #pragma unroll
    for (int p = 0; p < 4; ++p) {
        int r = ty + p * 8;
        t[r][tx] = src[(size_t)(r0 + r) * C + c0 + tx];
    }
    __syncthreads();
    #pragma unroll
    for (int p = 0; p < 4; ++p) {
        int oc = ty + p * 8;
        float v = t[tx][oc] * scale;
        _Float16 h = (_Float16)v;
        size_t o = (size_t)(c0 + oc) * R + r0 + tx;
        hi[o] = h;
        lo[o] = (_Float16)(v - (float)h);
    }
}

// ---------------------------------------------------------------------------
// Normalize codebook rows (fp32 math), emit scaled f16 hi/lo [K][E].
// ---------------------------------------------------------------------------
__global__ __launch_bounds__(256)
void norm_codes(const float* __restrict__ emb, _Float16* __restrict__ cnHi,
                _Float16* __restrict__ cnLo)
{
    int wave = threadIdx.x >> 6;
    int lane = threadIdx.x & 63;
    int c = blockIdx.x * 4 + wave;
    if (c >= KCODE) return;
    const float* er = emb + (size_t)c * EMB;
    float ss = 0.0f;
    #pragma unroll
    for (int k = lane; k < EMB; k += 64) { float v = er[k]; ss += v * v; }
    #pragma unroll
    for (int off = 32; off > 0; off >>= 1) ss += __shfl_down(ss, off, 64);
    ss = __shfl(ss, 0, 64);
    float inv = 1.0f / (sqrtf(ss) + 1e-12f);
    #pragma unroll
    for (int k = lane; k < EMB; k += 64) {
        float v = er[k] * inv * SC_CODE;
        _Float16 h = (_Float16)v;
        cnHi[(size_t)c * EMB + k] = h;
        cnLo[(size_t)c * EMB + k] = (_Float16)(v - (float)h);
    }
}

// ---------------------------------------------------------------------------
// Argmax over sim rows, where sim[row][c] = p0[row][c] + p1[row][c]
// (2 split-K partials; positive common scale is argmax-invariant, so no
// descale). Writes one-hot, vq_feat gather, AND decoded row (gather from
// precomputed decoder output Dcode[bestI]) -- fused, no idx round-trip.
// First-index tie-break.
// ---------------------------------------------------------------------------
__global__ __launch_bounds__(256)
void argmax_vq2(const float* __restrict__ part, int MN,
                const float* __restrict__ emb,
                const float* __restrict__ Dcode,
                float* __restrict__ onehot, float* __restrict__ vqfeat,
                float* __restrict__ decoded)
{
    int wave = threadIdx.x >> 6;
    int lane = threadIdx.x & 63;
    int row = blockIdx.x * 4 + wave;
    if (row >= BATCH) return;

    const float* p0 = part + (size_t)row * KCODE;
    const float* p1 = part + (size_t)MN + (size_t)row * KCODE;
    float bestV = -3.402823466e+38f;
    int   bestI = 0;
    #pragma unroll
    for (int c = lane; c < KCODE; c += 64) {
        float v = p0[c] + p1[c];
        if (v > bestV) { bestV = v; bestI = c; }
    }
    #pragma unroll
    for (int off = 32; off > 0; off >>= 1) {
        float ov = __shfl_down(bestV, off, 64);
        int   oi = __shfl_down(bestI, off, 64);
        if (ov > bestV || (ov == bestV && oi < bestI)) { bestV = ov; bestI = oi; }
    }
    bestI = __shfl(bestI, 0, 64);

    float* oh = onehot + (size_t)row * KCODE;
    #pragma unroll
    for (int c = lane; c < KCODE; c += 64) oh[c] = (c == bestI) ? 1.0f : 0.0f;

    const float* er = emb + (size_t)bestI * EMB;
    float* vr = vqfeat + (size_t)row * EMB;
    #pragma unroll
    for (int c = lane; c < EMB; c += 64) vr[c] = er[c];

    // fused gather: decoded[row] = Dcode[bestI]
    const float4* sd = (const float4*)(Dcode + (size_t)bestI * FEAT);
    float4* dd = (float4*)(decoded + (size_t)row * FEAT);
    #pragma unroll
    for (int i = lane; i < FEAT / 4; i += 64) dd[i] = sd[i];
}

__global__ __launch_bounds__(256)
void copy_f4(const float* __restrict__ src, float* __restrict__ dst, int n4)
{
    int i = blockIdx.x * 256 + threadIdx.x;
    if (i < n4) ((float4*)dst)[i] = ((const float4*)src)[i];
}

// ---------------------------------------------------------------------------
extern "C" void kernel_launch(void* const* d_in, const int* in_sizes, int n_in,
                              void* d_out, int out_size, void* d_ws, size_t ws_size,
                              hipStream_t stream)
{
    const float* x      = (const float*)d_in[0];
    const float* enc_w1 = (const float*)d_in[1];
    const float* enc_b1 = (const float*)d_in[2];
    const float* enc_w2 = (const float*)d_in[3];
    const float* enc_b2 = (const float*)d_in[4];
    const float* emb    = (const float*)d_in[5];
    const float* dec_w1 = (const float*)d_in[6];
    const float* dec_b1 = (const float*)d_in[7];
    const float* dec_w2 = (const float*)d_in[8];
    const float* dec_b2 = (const float*)d_in[9];

    float* out = (float*)d_out;
    float* out_encoded = out;
    float* out_vqfeat  = out + (size_t)BATCH * EMB;
    float* out_onehot  = out + (size_t)2 * BATCH * EMB;
    float* out_decoded = out + (size_t)2 * BATCH * EMB + (size_t)BATCH * KCODE;
    float* out_emb     = out_decoded + (size_t)BATCH * FEAT;

    // x hi/lo scratch lives in the out_decoded region (BATCH*FEAT*4 bytes ==
    // exactly 2 f16 planes). decoded is only written at the very end (argmax),
    // long after G1 has consumed xhi/xlo.
    _Float16* x_hi = (_Float16*)out_decoded;
    _Float16* x_lo = x_hi + (size_t)BATCH * FEAT;

    // ------- workspace layout (~116 MB) -------
    char* w = (char*)d_ws;
    _Float16* w1T_hi = (_Float16*)w;  w += (size_t)FEAT * MID * 2;
    _Float16* w1T_lo = (_Float16*)w;  w += (size_t)FEAT * MID * 2;
    _Float16* w2T_hi = (_Float16*)w;  w += (size_t)MID * EMB * 2;
    _Float16* w2T_lo = (_Float16*)w;  w += (size_t)MID * EMB * 2;
    _Float16* wd1T_hi= (_Float16*)w;  w += (size_t)MID * EMB * 2;
    _Float16* wd1T_lo= (_Float16*)w;  w += (size_t)MID * EMB * 2;
    _Float16* wd2T_hi= (_Float16*)w;  w += (size_t)FEAT * MID * 2;
    _Float16* wd2T_lo= (_Float16*)w;  w += (size_t)FEAT * MID * 2;
    _Float16* h_hi   = (_Float16*)w;  w += (size_t)BATCH * MID * 2;
    _Float16* h_lo   = (_Float16*)w;  w += (size_t)BATCH * MID * 2;
    _Float16* enc_hi = (_Float16*)w;  w += (size_t)BATCH * EMB * 2;
    _Float16* enc_lo = (_Float16*)w;  w += (size_t)BATCH * EMB * 2;
    _Float16* cn_hi  = (_Float16*)w;  w += (size_t)KCODE * EMB * 2;
    _Float16* cn_lo  = (_Float16*)w;  w += (size_t)KCODE * EMB * 2;
    _Float16* tm_hi  = (_Float16*)w;  w += (size_t)KCODE * MID * 2;
    _Float16* tm_lo  = (_Float16*)w;  w += (size_t)KCODE * MID * 2;
    float*    Dc     = (float*)w;     w += (size_t)KCODE * FEAT * 4;
    float*    scr    = (float*)w;     w += (size_t)4 * BATCH * MID * 4;  // 64 MB, reused

    // --- prep: weight transposes/splits, codebook norm, emb passthrough ---
    transpose_split<<<dim3(MID / 32, FEAT / 32), dim3(256), 0, stream>>>(
        enc_w1, w1T_hi, w1T_lo, SC_W, FEAT, MID);
    transpose_split<<<dim3(EMB / 32, MID / 32), dim3(256), 0, stream>>>(
        enc_w2, w2T_hi, w2T_lo, SC_W, MID, EMB);
    transpose_split<<<dim3(MID / 32, EMB / 32), dim3(256), 0, stream>>>(
        dec_w1, wd1T_hi, wd1T_lo, SC_W, EMB, MID);
    transpose_split<<<dim3(FEAT / 32, MID / 32), dim3(256), 0, stream>>>(
        dec_w2, wd2T_hi, wd2T_lo, SC_W, MID, FEAT);
    norm_codes<<<dim3(KCODE / 4), dim3(256), 0, stream>>>(emb, cn_hi, cn_lo);
    copy_f4<<<dim3((KCODE * EMB / 4 + 255) / 256), dim3(256), 0, stream>>>(
        emb, out_emb, KCODE * EMB / 4);

    // --- decoder on codebook only (512 distinct rows), 1-term f16.
    // Moved before the encoder chain: depends only on emb + dec weights, and
    // frees the dependency so the fused argmax can gather decoded directly.
    gemm_sk<1, 1><<<dim3(KCODE / 128, KCODE / 128), dim3(256), 0, stream>>>(
        emb, nullptr, nullptr, wd1T_hi, wd1T_lo, SC_EMB,
        nullptr, dec_b1, DS_D1, 1, nullptr, tm_hi, tm_lo, SC_TM,
        KCODE, MID, EMB, 0, 0, 0);
    gemm_sk<1, 0><<<dim3(FEAT / 128, KCODE / 128), dim3(256), 0, stream>>>(
        nullptr, tm_hi, tm_lo, wd2T_hi, wd2T_lo, 0.0f,
        nullptr, dec_b2, DS_D2, 1, Dc, nullptr, nullptr, 0.0f,
        KCODE, FEAT, MID, 0, 0, 0);

    // --- split x once (HBM-bound pass), then pure-GLD16 G1 ---
    split_scale<<<dim3(2048), dim3(256), 0, stream>>>(
        x, x_hi, x_lo, SC_X, BATCH * FEAT / 8);

    // --- G1: x @ w1 partials; split-K=4, 1024 blocks, swizzled, AF32=0
    gemm_sk<3, 0><<<dim3(1024), dim3(256), 0, stream>>>(
        nullptr, x_hi, x_lo, w1T_hi, w1T_lo, 0.0f,
        scr, nullptr, 0.0f, 0, nullptr, nullptr, nullptr, 0.0f,
        BATCH, MID, FEAT, 2, 2, 1);
    // red1: h = relu(sum * DS_G1 + b1) -> h hi/lo
    reduce_sk<<<dim3(BATCH * MID / 4 / 256), dim3(256), 0, stream>>>(
        scr, 4, BATCH * MID, MID, enc_b1, DS_G1, 1,
        nullptr, h_hi, h_lo, SC_H);

    // --- G2: h @ w2 partials; split-K=4, 512 blocks, swizzled
    gemm_sk<3, 0><<<dim3(512), dim3(256), 0, stream>>>(
        nullptr, h_hi, h_lo, w2T_hi, w2T_lo, 0.0f,
        scr, nullptr, 0.0f, 0, nullptr, nullptr, nullptr, 0.0f,
        BATCH, EMB, MID, 2, 1, 1);
    // red2: encoded = sum * DS_G2 + b2 -> fp32 out + enc hi/lo
    reduce_sk<<<dim3(BATCH * EMB / 4 / 256), dim3(256), 0, stream>>>(
        scr, 4, BATCH * EMB, EMB, enc_b2, DS_G2, 0,
        out_encoded, enc_hi, enc_lo, SC_ENC);

    // --- G3: enc @ cn^T partials; split-K=2, 512 blocks, swizzled
    gemm_sk<3, 0><<<dim3(512), dim3(256), 0, stream>>>(
        nullptr, enc_hi, enc_lo, cn_hi, cn_lo, 0.0f,
        scr, nullptr, 0.0f, 0, nullptr, nullptr, nullptr, 0.0f,
        BATCH, KCODE, EMB, 1, 2, 1);
    // --- argmax over (p0+p1): one-hot, vq_feat, fused decoded gather.
    // NOTE: this overwrites out_decoded, which until now held x_hi/x_lo --
    // G1 (the only consumer) has long completed.
    argmax_vq2<<<dim3(BATCH / 4), dim3(256), 0, stream>>>(
        scr, BATCH * KCODE, emb, Dc, out_onehot, out_vqfeat, out_decoded);
}

// Round 2
// 492.647 us; speedup vs baseline: 1.1122x; 1.1122x over previous
//
#include <hip/hip_runtime.h>

#define BATCH 8192
#define FEAT  4096
#define MID   512
#define EMB   256
#define KCODE 512

typedef _Float16 half8 __attribute__((ext_vector_type(8)));
typedef _Float16 half4v __attribute__((ext_vector_type(4)));
typedef float floatx4 __attribute__((ext_vector_type(4)));

// Power-of-2 scales; descaled exactly in epilogues/reduces.
#define SC_X    512.0f
#define SC_W    4096.0f
#define SC_H    512.0f
#define SC_ENC  4096.0f
#define SC_CODE 4096.0f
#define SC_EMB  4096.0f
#define SC_TM   512.0f
#define DS_G1   (1.0f / (SC_X   * SC_W))
#define DS_G2   (1.0f / (SC_H   * SC_W))
#define DS_D1   (1.0f / (SC_EMB * SC_W))
#define DS_D2   (1.0f / (SC_TM  * SC_W))

#define GLD16(gp, lp)                                                          \
    __builtin_amdgcn_global_load_lds(                                          \
        (const __attribute__((address_space(1))) void*)(gp),                   \
        (__attribute__((address_space(3))) void*)(lp), 16, 0, 0)

// ---------------------------------------------------------------------------
// Split-K MFMA GEMM, 128x128 tile, BK=32, 4 waves (2x2 of 64x64).
// C = A @ B^T (B pre-split/scaled f16 hi/lo, TRANSPOSED [N][K]).
// NT=3: hi*hi + hi*lo + lo*hi (fp32-equivalent). NT=1: hi only.
// AF32=1: A fp32, split in-register (T14: issue loads early, convert+ds_write
//         after the MFMA block). AF32=0: A pre-split hi/lo via GLD16.
//
// T3-minimum schedule (single barrier per K-step, double-buffered LDS):
//   iter i: issue stage(buf[nxt], k+32)   <- GLD16 / fp32 reg loads in flight
//           ds_read buf[cur]; 16/48 MFMA  <- load latency hides under this
//           (AF32: vmcnt-wait regs, convert, ds_write -> buf[nxt])
//           __syncthreads()               <- single drain+barrier per step
// Safety: GLD16/ds_write into buf[nxt] only touch the buffer whose readers
// finished at the PREVIOUS barrier; the barrier's implicit vmcnt(0)/lgkmcnt(0)
// per-wave drain publishes all staging before the next iter reads it.
//
// If partOut != null: raw fp32 accumulators to partOut[ks*M*N + ...].
// Else: final epilogue (descale, bias, relu, fp32 / hi-lo out).
// swz: 1-D grid, b -> {m_lo=b&7, ks, n, m_hi}; n/k-peers of an M-stripe share
// b%8 (same XCD) for L2-shared A; gridM%8==0 required.
// ---------------------------------------------------------------------------
template<int NT, int AF32>
__global__ __launch_bounds__(256)
void gemm_sk(const float* __restrict__ Af32,
             const _Float16* __restrict__ Ahg, const _Float16* __restrict__ Alg,
             const _Float16* __restrict__ BTh, const _Float16* __restrict__ BTl,
             float aScale,
             float* __restrict__ partOut,
             const float* __restrict__ bias, float descale, int relu,
             float* __restrict__ outF, _Float16* __restrict__ outHi,
             _Float16* __restrict__ outLo, float outScale,
             int M, int N, int K, int lgK, int lgN, int swz)
{
    __shared__ _Float16 AhS[2][128 * 32];
    __shared__ _Float16 BhS[2][128 * 32];
    __shared__ _Float16 AlS[NT == 3 ? 2 : 1][NT == 3 ? 128 * 32 : 8];
    __shared__ _Float16 BlS[NT == 3 ? 2 : 1][NT == 3 ? 128 * 32 : 8];

    const int tid  = threadIdx.x;
    const int lane = tid & 63;
    const int wave = tid >> 6;
    const int wm = wave >> 1, wn = wave & 1;
    const int l15  = lane & 15;
    const int quad = lane >> 4;
    const int q8   = quad * 8;

    int bm, bn, ks;
    if (swz) {
        int b = blockIdx.x;
        int mlo = b & 7;
        ks = (b >> 3) & ((1 << lgK) - 1);
        bn = (b >> (3 + lgK)) & ((1 << lgN) - 1);
        bm = ((b >> (3 + lgK + lgN)) << 3) | mlo;
    } else { bm = blockIdx.y; bn = blockIdx.x; ks = 0; }
    const int row0 = bm * 128, col0 = bn * 128;
    const int Kslice = K >> lgK;
    const int k0 = ks * Kslice;

    // GLD16 staging coords (64 rows per call; two calls = 128 rows)
    const int sr4 = tid >> 2;
    const int sc4 = (tid & 3) * 8;
    const size_t aB0 = (size_t)(row0 + sr4) * K + sc4;
    const size_t aB1 = (size_t)(row0 + 64 + sr4) * K + sc4;
    const size_t bB0 = (size_t)(col0 + sr4) * K + sc4;
    const size_t bB1 = (size_t)(col0 + 64 + sr4) * K + sc4;
    const int l0 = tid * 8, l1 = 2048 + tid * 8;

    // AF32 staging coords (one pass: 256 threads x 16 elems = 128x32)
    const int sr2 = tid >> 1;
    const int sk2 = (tid & 1) * 16;
    const size_t aOff2 = (size_t)(row0 + sr2) * K + sk2;
    const int lA = sr2 * 32 + sk2;

    floatx4 acc[4][4] = {};

    // convert 16 fp32 -> scaled f16 hi/lo, store to LDS buffer s
    auto cvtA = [&](int s, float4 f0, float4 f1, float4 f2, float4 f3) {
        float fv[16] = {f0.x,f0.y,f0.z,f0.w, f1.x,f1.y,f1.z,f1.w,
                        f2.x,f2.y,f2.z,f2.w, f3.x,f3.y,f3.z,f3.w};
        half8 hv0, hv1, lv0, lv1;
        #pragma unroll
        for (int e = 0; e < 8; ++e) {
            float v = fv[e] * aScale;
            _Float16 h = (_Float16)v;
            hv0[e] = h; lv0[e] = (_Float16)(v - (float)h);
        }
        #pragma unroll
        for (int e = 0; e < 8; ++e) {
            float v = fv[8 + e] * aScale;
            _Float16 h = (_Float16)v;
            hv1[e] = h; lv1[e] = (_Float16)(v - (float)h);
        }
        *(half8*)&AhS[s][lA] = hv0; *(half8*)&AhS[s][lA + 8] = hv1;
        if (NT == 3) {
            *(half8*)&AlS[s][lA] = lv0; *(half8*)&AlS[s][lA + 8] = lv1;
        }
    };

    const int Ksteps = Kslice >> 5;

    // ---- prologue: stage step 0 into buffer 0 ----
    {
        GLD16(BTh + bB0 + k0, &BhS[0][l0]);
        GLD16(BTh + bB1 + k0, &BhS[0][l1]);
        if (NT == 3) {
            GLD16(BTl + bB0 + k0, &BlS[0][l0]);
            GLD16(BTl + bB1 + k0, &BlS[0][l1]);
        }
        if (AF32) {
            const float* p = Af32 + aOff2 + k0;
            float4 f0 = *(const float4*)(p);
            float4 f1 = *(const float4*)(p + 4);
            float4 f2 = *(const float4*)(p + 8);
            float4 f3 = *(const float4*)(p + 12);
            cvtA(0, f0, f1, f2, f3);
        } else {
            GLD16(Ahg + aB0 + k0, &AhS[0][l0]);
            GLD16(Ahg + aB1 + k0, &AhS[0][l1]);
            if (NT == 3) {
                GLD16(Alg + aB0 + k0, &AlS[0][l0]);
                GLD16(Alg + aB1 + k0, &AlS[0][l1]);
            }
        }
    }
    __syncthreads();

    for (int it = 0; it < Ksteps; ++it) {
        const int cur = it & 1, nxt = cur ^ 1;
        const bool pf = (it + 1) < Ksteps;
        float4 f0, f1, f2, f3;
        // ---- issue next-tile staging (stays in flight during MFMA) ----
        if (pf) {
            const int kk = k0 + (it + 1) * 32;
            GLD16(BTh + bB0 + kk, &BhS[nxt][l0]);
            GLD16(BTh + bB1 + kk, &BhS[nxt][l1]);
            if (NT == 3) {
                GLD16(BTl + bB0 + kk, &BlS[nxt][l0]);
                GLD16(BTl + bB1 + kk, &BlS[nxt][l1]);
            }
            if (AF32) {
                const float* p = Af32 + aOff2 + kk;
                f0 = *(const float4*)(p);
                f1 = *(const float4*)(p + 4);
                f2 = *(const float4*)(p + 8);
                f3 = *(const float4*)(p + 12);
            } else {
                GLD16(Ahg + aB0 + kk, &AhS[nxt][l0]);
                GLD16(Ahg + aB1 + kk, &AhS[nxt][l1]);
                if (NT == 3) {
                    GLD16(Alg + aB0 + kk, &AlS[nxt][l0]);
                    GLD16(Alg + aB1 + kk, &AlS[nxt][l1]);
                }
            }
        }
        // ---- compute on current buffer ----
        half8 ah[4], al4[4], bh[4], bl4[4];
        #pragma unroll
        for (int i = 0; i < 4; ++i) {
            int ra = (wm * 64 + i * 16 + l15) * 32 + q8;
            int rb = (wn * 64 + i * 16 + l15) * 32 + q8;
            ah[i] = *(const half8*)&AhS[cur][ra];
            bh[i] = *(const half8*)&BhS[cur][rb];
            if (NT == 3) {
                al4[i] = *(const half8*)&AlS[cur][ra];
                bl4[i] = *(const half8*)&BlS[cur][rb];
            }
        }
        #pragma unroll
        for (int i = 0; i < 4; ++i)
            #pragma unroll
            for (int j = 0; j < 4; ++j) {
                acc[i][j] = __builtin_amdgcn_mfma_f32_16x16x32_f16(ah[i], bh[j], acc[i][j], 0, 0, 0);
                if (NT == 3) {
                    acc[i][j] = __builtin_amdgcn_mfma_f32_16x16x32_f16(ah[i],  bl4[j], acc[i][j], 0, 0, 0);
                    acc[i][j] = __builtin_amdgcn_mfma_f32_16x16x32_f16(al4[i], bh[j],  acc[i][j], 0, 0, 0);
                }
            }
        // ---- T14 commit: convert A regs (loads waited here, post-MFMA) ----
        if (AF32 && pf) cvtA(nxt, f0, f1, f2, f3);
        __syncthreads();
    }

    // Epilogue. C/D layout: col = lane&15, row = quad*4 + reg (verified m89).
    if (partOut) {
        float* po = partOut + (size_t)ks * M * N;
        #pragma unroll
        for (int j = 0; j < 4; ++j) {
            int col = col0 + wn * 64 + j * 16 + l15;
            #pragma unroll
            for (int i = 0; i < 4; ++i)
                #pragma unroll
                for (int t = 0; t < 4; ++t) {
                    int r = row0 + wm * 64 + i * 16 + quad * 4 + t;
                    po[(size_t)r * N + col] = acc[i][j][t];
                }
        }
    } else {
        #pragma unroll
        for (int j = 0; j < 4; ++j) {
            int col = col0 + wn * 64 + j * 16 + l15;
            float bcol = bias ? bias[col] : 0.0f;
            #pragma unroll
            for (int i = 0; i < 4; ++i)
                #pragma unroll
                for (int t = 0; t < 4; ++t) {
                    int r = row0 + wm * 64 + i * 16 + quad * 4 + t;
                    float v = acc[i][j][t] * descale + bcol;
                    if (relu) v = fmaxf(v, 0.0f);
                    size_t o = (size_t)r * N + col;
                    if (outF) outF[o] = v;
                    if (outHi) {
                        float sv = v * outScale;
                        _Float16 h = (_Float16)sv;
                        outHi[o] = h;
                        outLo[o] = (_Float16)(sv - (float)h);
                    }
                }
        }
    }
}

// ---------------------------------------------------------------------------
// Split-K reduce: out = relu( (sum_s part[s]) * descale + bias ), emitting
// fp32 and/or scaled f16 hi/lo. float4 per thread.
// ---------------------------------------------------------------------------
__global__ __launch_bounds__(256)
void reduce_sk(const float* __restrict__ part, int nSlice, int MN, int N,
               const float* __restrict__ bias, float descale, int relu,
               float* __restrict__ outF, _Float16* __restrict__ outHi,
               _Float16* __restrict__ outLo, float outScale)
{
    int i = blockIdx.x * 256 + threadIdx.x;
    if (i * 4 >= MN) return;
    float4 s = ((const float4*)part)[i];
    for (int sl = 1; sl < nSlice; ++sl) {
        float4 p = ((const float4*)(part + (size_t)sl * MN))[i];
        s.x += p.x; s.y += p.y; s.z += p.z; s.w += p.w;
    }
    int col = (i * 4) % N;
    float v[4] = {s.x, s.y, s.z, s.w};
    #pragma unroll
    for (int e = 0; e < 4; ++e) {
        float t = v[e] * descale + (bias ? bias[col + e] : 0.0f);
        if (relu) t = fmaxf(t, 0.0f);
        v[e] = t;
    }
    if (outF) ((float4*)outF)[i] = *(float4*)v;
    if (outHi) {
        half4v hv, lv;
        #pragma unroll
        for (int e = 0; e < 4; ++e) {
            float sv = v[e] * outScale;
            _Float16 h = (_Float16)sv;
            hv[e] = h;
            lv[e] = (_Float16)(sv - (float)h);
        }
        ((half4v*)outHi)[i] = hv;
        ((half4v*)outLo)[i] = lv;
    }
}

// ---------------------------------------------------------------------------
// Transpose fp32 [R][C] -> scaled f16 hi/lo [C][R]. 32x32 LDS tiles.
// ---------------------------------------------------------------------------
__global__ __launch_bounds__(256)
void transpose_split(const float* __restrict__ src, _Float16* __restrict__ hi,
                     _Float16* __restrict__ lo, float scale, int R, int C)
{
    __shared__ float t[32][33];
    int tx = threadIdx.x & 31, ty = threadIdx.x >> 5;
    int r0 = blockIdx.y * 32, c0 = blockIdx.x * 32;
    #pragma unroll
    for (int p = 0; p < 4; ++p) {
        int r = ty + p * 8;
        t[r][tx] = src[(size_t)(r0 + r) * C + c0 + tx];
    }
    __syncthreads();
    #pragma unroll
    for (int p = 0; p < 4; ++p) {
        int oc = ty + p * 8;
        float v = t[tx][oc] * scale;
        _Float16 h = (_Float16)v;
        size_t o = (size_t)(c0 + oc) * R + r0 + tx;
        hi[o] = h;
        lo[o] = (_Float16)(v - (float)h);
    }
}

// ---------------------------------------------------------------------------
// Normalize codebook rows (fp32 math), emit scaled f16 hi/lo [K][E].
// ---------------------------------------------------------------------------
__global__ __launch_bounds__(256)
void norm_codes(const float* __restrict__ emb, _Float16* __restrict__ cnHi,
                _Float16* __restrict__ cnLo)
{
    int wave = threadIdx.x >> 6;
    int lane = threadIdx.x & 63;
    int c = blockIdx.x * 4 + wave;
    if (c >= KCODE) return;
    const float* er = emb + (size_t)c * EMB;
    float ss = 0.0f;
    #pragma unroll
    for (int k = lane; k < EMB; k += 64) { float v = er[k]; ss += v * v; }
    #pragma unroll
    for (int off = 32; off > 0; off >>= 1) ss += __shfl_down(ss, off, 64);
    ss = __shfl(ss, 0, 64);
    float inv = 1.0f / (sqrtf(ss) + 1e-12f);
    #pragma unroll
    for (int k = lane; k < EMB; k += 64) {
        float v = er[k] * inv * SC_CODE;
        _Float16 h = (_Float16)v;
        cnHi[(size_t)c * EMB + k] = h;
        cnLo[(size_t)c * EMB + k] = (_Float16)(v - (float)h);
    }
}

// ---------------------------------------------------------------------------
// Argmax + fused outputs, one block (256 thr) per row for full gather BW.
// sim[row][c] = p0[row][c] + p1[row][c] (2 split-K partials; positive common
// scale is argmax-invariant). Wave 0 finds argmax (first-index tie-break),
// broadcast via LDS, then ALL 256 threads write onehot, vqfeat, decoded
// (gather of precomputed Dcode[bestI]).
// ---------------------------------------------------------------------------
__global__ __launch_bounds__(256)
void argmax_vq3(const float* __restrict__ part, int MN,
                const float* __restrict__ emb,
                const float* __restrict__ Dcode,
                float* __restrict__ onehot, float* __restrict__ vqfeat,
                float* __restrict__ decoded)
{
    __shared__ int sBest;
    const int row = blockIdx.x;
    const int tid = threadIdx.x;

    if (tid < 64) {
        const float* p0 = part + (size_t)row * KCODE;
        const float* p1 = part + (size_t)MN + (size_t)row * KCODE;
        float bestV = -3.402823466e+38f;
        int   bestI = 0;
        #pragma unroll
        for (int c = tid; c < KCODE; c += 64) {
            float v = p0[c] + p1[c];
            if (v > bestV) { bestV = v; bestI = c; }
        }
        #pragma unroll
        for (int off = 32; off > 0; off >>= 1) {
            float ov = __shfl_down(bestV, off, 64);
            int   oi = __shfl_down(bestI, off, 64);
            if (ov > bestV || (ov == bestV && oi < bestI)) { bestV = ov; bestI = oi; }
        }
        if (tid == 0) sBest = bestI;
    }
    __syncthreads();
    const int bestI = sBest;

    float* oh = onehot + (size_t)row * KCODE;
    oh[tid]       = (tid       == bestI) ? 1.0f : 0.0f;
    oh[tid + 256] = (tid + 256 == bestI) ? 1.0f : 0.0f;

    vqfeat[(size_t)row * EMB + tid] = emb[(size_t)bestI * EMB + tid];

    const float4* sd = (const float4*)(Dcode + (size_t)bestI * FEAT);
    float4* dd = (float4*)(decoded + (size_t)row * FEAT);
    #pragma unroll
    for (int i = tid; i < FEAT / 4; i += 256) dd[i] = sd[i];
}

__global__ __launch_bounds__(256)
void copy_f4(const float* __restrict__ src, float* __restrict__ dst, int n4)
{
    int i = blockIdx.x * 256 + threadIdx.x;
    if (i < n4) ((float4*)dst)[i] = ((const float4*)src)[i];
}

// ---------------------------------------------------------------------------
extern "C" void kernel_launch(void* const* d_in, const int* in_sizes, int n_in,
                              void* d_out, int out_size, void* d_ws, size_t ws_size,
                              hipStream_t stream)
{
    const float* x      = (const float*)d_in[0];
    const float* enc_w1 = (const float*)d_in[1];
    const float* enc_b1 = (const float*)d_in[2];
    const float* enc_w2 = (const float*)d_in[3];
    const float* enc_b2 = (const float*)d_in[4];
    const float* emb    = (const float*)d_in[5];
    const float* dec_w1 = (const float*)d_in[6];
    const float* dec_b1 = (const float*)d_in[7];
    const float* dec_w2 = (const float*)d_in[8];
    const float* dec_b2 = (const float*)d_in[9];

    float* out = (float*)d_out;
    float* out_encoded = out;
    float* out_vqfeat  = out + (size_t)BATCH * EMB;
    float* out_onehot  = out + (size_t)2 * BATCH * EMB;
    float* out_decoded = out + (size_t)2 * BATCH * EMB + (size_t)BATCH * KCODE;
    float* out_emb     = out_decoded + (size_t)BATCH * FEAT;

    // ------- workspace layout (~116 MB) -------
    char* w = (char*)d_ws;
    _Float16* w1T_hi = (_Float16*)w;  w += (size_t)FEAT * MID * 2;
    _Float16* w1T_lo = (_Float16*)w;  w += (size_t)FEAT * MID * 2;
    _Float16* w2T_hi = (_Float16*)w;  w += (size_t)MID * EMB * 2;
    _Float16* w2T_lo = (_Float16*)w;  w += (size_t)MID * EMB * 2;
    _Float16* wd1T_hi= (_Float16*)w;  w += (size_t)MID * EMB * 2;
    _Float16* wd1T_lo= (_Float16*)w;  w += (size_t)MID * EMB * 2;
    _Float16* wd2T_hi= (_Float16*)w;  w += (size_t)FEAT * MID * 2;
    _Float16* wd2T_lo= (_Float16*)w;  w += (size_t)FEAT * MID * 2;
    _Float16* h_hi   = (_Float16*)w;  w += (size_t)BATCH * MID * 2;
    _Float16* h_lo   = (_Float16*)w;  w += (size_t)BATCH * MID * 2;
    _Float16* enc_hi = (_Float16*)w;  w += (size_t)BATCH * EMB * 2;
    _Float16* enc_lo = (_Float16*)w;  w += (size_t)BATCH * EMB * 2;
    _Float16* cn_hi  = (_Float16*)w;  w += (size_t)KCODE * EMB * 2;
    _Float16* cn_lo  = (_Float16*)w;  w += (size_t)KCODE * EMB * 2;
    _Float16* tm_hi  = (_Float16*)w;  w += (size_t)KCODE * MID * 2;
    _Float16* tm_lo  = (_Float16*)w;  w += (size_t)KCODE * MID * 2;
    float*    Dc     = (float*)w;     w += (size_t)KCODE * FEAT * 4;
    float*    scr    = (float*)w;     w += (size_t)4 * BATCH * MID * 4;  // 64 MB, reused

    // --- prep: weight transposes/splits, codebook norm, emb passthrough ---
    transpose_split<<<dim3(MID / 32, FEAT / 32), dim3(256), 0, stream>>>(
        enc_w1, w1T_hi, w1T_lo, SC_W, FEAT, MID);
    transpose_split<<<dim3(EMB / 32, MID / 32), dim3(256), 0, stream>>>(
        enc_w2, w2T_hi, w2T_lo, SC_W, MID, EMB);
    transpose_split<<<dim3(MID / 32, EMB / 32), dim3(256), 0, stream>>>(
        dec_w1, wd1T_hi, wd1T_lo, SC_W, EMB, MID);
    transpose_split<<<dim3(FEAT / 32, MID / 32), dim3(256), 0, stream>>>(
        dec_w2, wd2T_hi, wd2T_lo, SC_W, MID, FEAT);
    norm_codes<<<dim3(KCODE / 4), dim3(256), 0, stream>>>(emb, cn_hi, cn_lo);
    copy_f4<<<dim3((KCODE * EMB / 4 + 255) / 256), dim3(256), 0, stream>>>(
        emb, out_emb, KCODE * EMB / 4);

    // --- decoder on codebook only (512 distinct rows), 1-term f16 ---
    gemm_sk<1, 1><<<dim3(KCODE / 128, KCODE / 128), dim3(256), 0, stream>>>(
        emb, nullptr, nullptr, wd1T_hi, wd1T_lo, SC_EMB,
        nullptr, dec_b1, DS_D1, 1, nullptr, tm_hi, tm_lo, SC_TM,
        KCODE, MID, EMB, 0, 0, 0);
    gemm_sk<1, 0><<<dim3(FEAT / 128, KCODE / 128), dim3(256), 0, stream>>>(
        nullptr, tm_hi, tm_lo, wd2T_hi, wd2T_lo, 0.0f,
        nullptr, dec_b2, DS_D2, 1, Dc, nullptr, nullptr, 0.0f,
        KCODE, FEAT, MID, 0, 0, 0);

    // --- G1: x @ w1 partials; split-K=4, 1024 blocks, swizzled, AF32=1
    // (in-loop split with T14 prefetch; no pre-split pass)
    gemm_sk<3, 1><<<dim3(1024), dim3(256), 0, stream>>>(
        x, nullptr, nullptr, w1T_hi, w1T_lo, SC_X,
        scr, nullptr, 0.0f, 0, nullptr, nullptr, nullptr, 0.0f,
        BATCH, MID, FEAT, 2, 2, 1);
    // red1: h = relu(sum * DS_G1 + b1) -> h hi/lo
    reduce_sk<<<dim3(BATCH * MID / 4 / 256), dim3(256), 0, stream>>>(
        scr, 4, BATCH * MID, MID, enc_b1, DS_G1, 1,
        nullptr, h_hi, h_lo, SC_H);

    // --- G2: h @ w2 partials; split-K=4, 512 blocks, swizzled
    gemm_sk<3, 0><<<dim3(512), dim3(256), 0, stream>>>(
        nullptr, h_hi, h_lo, w2T_hi, w2T_lo, 0.0f,
        scr, nullptr, 0.0f, 0, nullptr, nullptr, nullptr, 0.0f,
        BATCH, EMB, MID, 2, 1, 1);
    // red2: encoded = sum * DS_G2 + b2 -> fp32 out + enc hi/lo
    reduce_sk<<<dim3(BATCH * EMB / 4 / 256), dim3(256), 0, stream>>>(
        scr, 4, BATCH * EMB, EMB, enc_b2, DS_G2, 0,
        out_encoded, enc_hi, enc_lo, SC_ENC);

    // --- G3: enc @ cn^T partials; split-K=2, 512 blocks, swizzled
    gemm_sk<3, 0><<<dim3(512), dim3(256), 0, stream>>>(
        nullptr, enc_hi, enc_lo, cn_hi, cn_lo, 0.0f,
        scr, nullptr, 0.0f, 0, nullptr, nullptr, nullptr, 0.0f,
        BATCH, KCODE, EMB, 1, 2, 1);
    // --- argmax over (p0+p1): one-hot, vq_feat, fused decoded gather
    argmax_vq3<<<dim3(BATCH), dim3(256), 0, stream>>>(
        scr, BATCH * KCODE, emb, Dc, out_onehot, out_vqfeat, out_decoded);
}

// Round 3
// 486.989 us; speedup vs baseline: 1.1251x; 1.0116x over previous
//
#include <hip/hip_runtime.h>

#define BATCH 8192
#define FEAT  4096
#define MID   512
#define EMB   256
#define KCODE 512

typedef _Float16 half8 __attribute__((ext_vector_type(8)));
typedef _Float16 half4v __attribute__((ext_vector_type(4)));
typedef float floatx4 __attribute__((ext_vector_type(4)));

// Power-of-2 scales; descaled exactly in epilogues/reduces.
#define SC_X    512.0f
#define SC_W    4096.0f
#define SC_H    512.0f
#define SC_ENC  4096.0f
#define SC_CODE 4096.0f
#define SC_EMB  4096.0f
#define SC_TM   512.0f
#define DS_G1   (1.0f / (SC_X   * SC_W))
#define DS_G2   (1.0f / (SC_H   * SC_W))
#define DS_D1   (1.0f / (SC_EMB * SC_W))
#define DS_D2   (1.0f / (SC_TM  * SC_W))

#define GLD16(gp, lp)                                                          \
    __builtin_amdgcn_global_load_lds(                                          \
        (const __attribute__((address_space(1))) void*)(gp),                   \
        (__attribute__((address_space(3))) void*)(lp), 16, 0, 0)

// ---------------------------------------------------------------------------
// Split-K MFMA GEMM, 128x128 tile, BK=32, 4 waves (2x2 of 64x64).
// C = A @ B^T (B pre-split/scaled f16 hi/lo, TRANSPOSED [N][K]).
// NT=3: hi*hi + hi*lo + lo*hi (fp32-equivalent). NT=1: hi only.
// AF32=1: A fp32, split in-register; f32 loads issued FIRST each iter so the
//         compiler's auto-wait before cvt leaves the B GLD16s in flight.
//
// T4 counted-vmcnt schedule (raw barriers, never vmcnt(0) mid-loop):
//   iter t: issue 8 staging loads -> buf[nxt]
//           s_waitcnt vmcnt(8)   <- waits iter t-1's loads only (mine stay)
//           s_barrier            <- all waves' buf[cur] staging landed
//           ds_read buf[cur]; MFMA (compiler-managed lgkm deps)
//           (AF32: cvt + ds_write -> buf[nxt]; lgkmcnt(0))
//           s_barrier            <- buf[cur] readers done; next iter may issue
// Safety: barrier2(t-1) orders buf[nxt] reads before iter-t GLD issue;
// vmcnt(count-issued-this-iter) + barrier1 publishes buf[cur] staging.
// Last iter issues nothing -> waits vmcnt(0).
//
// If partOut != null: raw fp32 accumulators to partOut[ks*M*N + ...].
// Else: final epilogue (descale, bias, relu, fp32 / hi-lo out).
// swz: 1-D grid, b -> {m_lo=b&7, ks, n, m_hi}; n/k-peers of an M-stripe share
// b%8 (same XCD) for L2-shared A; gridM%8==0 required.
// ---------------------------------------------------------------------------
template<int NT, int AF32>
__global__ __launch_bounds__(256)
void gemm_sk(const float* __restrict__ Af32,
             const _Float16* __restrict__ Ahg, const _Float16* __restrict__ Alg,
             const _Float16* __restrict__ BTh, const _Float16* __restrict__ BTl,
             float aScale,
             float* __restrict__ partOut,
             const float* __restrict__ bias, float descale, int relu,
             float* __restrict__ outF, _Float16* __restrict__ outHi,
             _Float16* __restrict__ outLo, float outScale,
             int M, int N, int K, int lgK, int lgN, int swz)
{
    __shared__ _Float16 AhS[2][128 * 32];
    __shared__ _Float16 BhS[2][128 * 32];
    __shared__ _Float16 AlS[NT == 3 ? 2 : 1][NT == 3 ? 128 * 32 : 8];
    __shared__ _Float16 BlS[NT == 3 ? 2 : 1][NT == 3 ? 128 * 32 : 8];

    const int tid  = threadIdx.x;
    const int lane = tid & 63;
    const int wave = tid >> 6;
    const int wm = wave >> 1, wn = wave & 1;
    const int l15  = lane & 15;
    const int quad = lane >> 4;
    const int q8   = quad * 8;

    int bm, bn, ks;
    if (swz) {
        int b = blockIdx.x;
        int mlo = b & 7;
        ks = (b >> 3) & ((1 << lgK) - 1);
        bn = (b >> (3 + lgK)) & ((1 << lgN) - 1);
        bm = ((b >> (3 + lgK + lgN)) << 3) | mlo;
    } else { bm = blockIdx.y; bn = blockIdx.x; ks = 0; }
    const int row0 = bm * 128, col0 = bn * 128;
    const int Kslice = K >> lgK;
    const int k0 = ks * Kslice;

    // GLD16 staging coords (64 rows per call; two calls = 128 rows)
    const int sr4 = tid >> 2;
    const int sc4 = (tid & 3) * 8;
    const size_t aB0 = (size_t)(row0 + sr4) * K + sc4;
    const size_t aB1 = (size_t)(row0 + 64 + sr4) * K + sc4;
    const size_t bB0 = (size_t)(col0 + sr4) * K + sc4;
    const size_t bB1 = (size_t)(col0 + 64 + sr4) * K + sc4;
    const int l0 = tid * 8, l1 = 2048 + tid * 8;

    // AF32 staging coords (one pass: 256 threads x 16 elems = 128x32)
    const int sr2 = tid >> 1;
    const int sk2 = (tid & 1) * 16;
    const size_t aOff2 = (size_t)(row0 + sr2) * K + sk2;
    const int lA = sr2 * 32 + sk2;

    floatx4 acc[4][4] = {};

    // convert 16 fp32 -> scaled f16 hi/lo, store to LDS buffer s
    auto cvtA = [&](int s, float4 f0, float4 f1, float4 f2, float4 f3) {
        float fv[16] = {f0.x,f0.y,f0.z,f0.w, f1.x,f1.y,f1.z,f1.w,
                        f2.x,f2.y,f2.z,f2.w, f3.x,f3.y,f3.z,f3.w};
        half8 hv0, hv1, lv0, lv1;
        #pragma unroll
        for (int e = 0; e < 8; ++e) {
            float v = fv[e] * aScale;
            _Float16 h = (_Float16)v;
            hv0[e] = h; lv0[e] = (_Float16)(v - (float)h);
        }
        #pragma unroll
        for (int e = 0; e < 8; ++e) {
            float v = fv[8 + e] * aScale;
            _Float16 h = (_Float16)v;
            hv1[e] = h; lv1[e] = (_Float16)(v - (float)h);
        }
        *(half8*)&AhS[s][lA] = hv0; *(half8*)&AhS[s][lA + 8] = hv1;
        if (NT == 3) {
            *(half8*)&AlS[s][lA] = lv0; *(half8*)&AlS[s][lA + 8] = lv1;
        }
    };

    const int Ksteps = Kslice >> 5;

    // ---- prologue: stage step 0 into buffer 0 ----
    {
        if (AF32) {
            const float* p = Af32 + aOff2 + k0;
            float4 f0 = *(const float4*)(p);
            float4 f1 = *(const float4*)(p + 4);
            float4 f2 = *(const float4*)(p + 8);
            float4 f3 = *(const float4*)(p + 12);
            cvtA(0, f0, f1, f2, f3);
        } else {
            GLD16(Ahg + aB0 + k0, &AhS[0][l0]);
            GLD16(Ahg + aB1 + k0, &AhS[0][l1]);
            if (NT == 3) {
                GLD16(Alg + aB0 + k0, &AlS[0][l0]);
                GLD16(Alg + aB1 + k0, &AlS[0][l1]);
            }
        }
        GLD16(BTh + bB0 + k0, &BhS[0][l0]);
        GLD16(BTh + bB1 + k0, &BhS[0][l1]);
        if (NT == 3) {
            GLD16(BTl + bB0 + k0, &BlS[0][l0]);
            GLD16(BTl + bB1 + k0, &BlS[0][l1]);
        }
        if (AF32) {
            // publish prologue ds_writes before iter-0's barrier1
            asm volatile("s_waitcnt lgkmcnt(0)" ::: "memory");
        }
    }

    for (int it = 0; it < Ksteps; ++it) {
        const int cur = it & 1, nxt = cur ^ 1;
        const bool pf = (it + 1) < Ksteps;
        float4 f0, f1, f2, f3;
        // ---- issue next-tile staging (stays in flight through barrier1) ----
        if (pf) {
            const int kk = k0 + (it + 1) * 32;
            if (AF32) {
                // f32 reg loads FIRST (compiler's cvt-wait then spares B GLDs)
                const float* p = Af32 + aOff2 + kk;
                f0 = *(const float4*)(p);
                f1 = *(const float4*)(p + 4);
                f2 = *(const float4*)(p + 8);
                f3 = *(const float4*)(p + 12);
            } else {
                GLD16(Ahg + aB0 + kk, &AhS[nxt][l0]);
                GLD16(Ahg + aB1 + kk, &AhS[nxt][l1]);
                if (NT == 3) {
                    GLD16(Alg + aB0 + kk, &AlS[nxt][l0]);
                    GLD16(Alg + aB1 + kk, &AlS[nxt][l1]);
                }
            }
            GLD16(BTh + bB0 + kk, &BhS[nxt][l0]);
            GLD16(BTh + bB1 + kk, &BhS[nxt][l1]);
            if (NT == 3) {
                GLD16(BTl + bB0 + kk, &BlS[nxt][l0]);
                GLD16(BTl + bB1 + kk, &BlS[nxt][l1]);
            }
            // counted wait: only the PREVIOUS iter's staging must have landed
            if constexpr (NT == 3)
                asm volatile("s_waitcnt vmcnt(8)" ::: "memory");
            else if constexpr (AF32)
                asm volatile("s_waitcnt vmcnt(6)" ::: "memory");
            else
                asm volatile("s_waitcnt vmcnt(4)" ::: "memory");
        } else {
            asm volatile("s_waitcnt vmcnt(0)" ::: "memory");
        }
        __builtin_amdgcn_s_barrier();   // raw: this iter's loads stay in flight

        // ---- compute on current buffer ----
        half8 ah[4], al4[4], bh[4], bl4[4];
        #pragma unroll
        for (int i = 0; i < 4; ++i) {
            int ra = (wm * 64 + i * 16 + l15) * 32 + q8;
            int rb = (wn * 64 + i * 16 + l15) * 32 + q8;
            ah[i] = *(const half8*)&AhS[cur][ra];
            bh[i] = *(const half8*)&BhS[cur][rb];
            if (NT == 3) {
                al4[i] = *(const half8*)&AlS[cur][ra];
                bl4[i] = *(const half8*)&BlS[cur][rb];
            }
        }
        #pragma unroll
        for (int i = 0; i < 4; ++i)
            #pragma unroll
            for (int j = 0; j < 4; ++j) {
                acc[i][j] = __builtin_amdgcn_mfma_f32_16x16x32_f16(ah[i], bh[j], acc[i][j], 0, 0, 0);
                if (NT == 3) {
                    acc[i][j] = __builtin_amdgcn_mfma_f32_16x16x32_f16(ah[i],  bl4[j], acc[i][j], 0, 0, 0);
                    acc[i][j] = __builtin_amdgcn_mfma_f32_16x16x32_f16(al4[i], bh[j],  acc[i][j], 0, 0, 0);
                }
            }
        // ---- T14 commit: convert A regs (loads waited here, post-MFMA) ----
        if (AF32 && pf) {
            cvtA(nxt, f0, f1, f2, f3);
            // publish ds_writes to other waves before barrier2
            asm volatile("s_waitcnt lgkmcnt(0)" ::: "memory");
        }
        __builtin_amdgcn_s_barrier();   // buf[cur] readers done
    }

    // Epilogue. C/D layout: col = lane&15, row = quad*4 + reg (verified m89).
    if (partOut) {
        float* po = partOut + (size_t)ks * M * N;
        #pragma unroll
        for (int j = 0; j < 4; ++j) {
            int col = col0 + wn * 64 + j * 16 + l15;
            #pragma unroll
            for (int i = 0; i < 4; ++i)
                #pragma unroll
                for (int t = 0; t < 4; ++t) {
                    int r = row0 + wm * 64 + i * 16 + quad * 4 + t;
                    po[(size_t)r * N + col] = acc[i][j][t];
                }
        }
    } else {
        #pragma unroll
        for (int j = 0; j < 4; ++j) {
            int col = col0 + wn * 64 + j * 16 + l15;
            float bcol = bias ? bias[col] : 0.0f;
            #pragma unroll
            for (int i = 0; i < 4; ++i)
                #pragma unroll
                for (int t = 0; t < 4; ++t) {
                    int r = row0 + wm * 64 + i * 16 + quad * 4 + t;
                    float v = acc[i][j][t] * descale + bcol;
                    if (relu) v = fmaxf(v, 0.0f);
                    size_t o = (size_t)r * N + col;
                    if (outF) outF[o] = v;
                    if (outHi) {
                        float sv = v * outScale;
                        _Float16 h = (_Float16)sv;
                        outHi[o] = h;
                        outLo[o] = (_Float16)(sv - (float)h);
                    }
                }
        }
    }
}

// ---------------------------------------------------------------------------
// Split-K reduce: out = relu( (sum_s part[s]) * descale + bias ), emitting
// fp32 and/or scaled f16 hi/lo. float4 per thread.
// ---------------------------------------------------------------------------
__global__ __launch_bounds__(256)
void reduce_sk(const float* __restrict__ part, int nSlice, int MN, int N,
               const float* __restrict__ bias, float descale, int relu,
               float* __restrict__ outF, _Float16* __restrict__ outHi,
               _Float16* __restrict__ outLo, float outScale)
{
    int i = blockIdx.x * 256 + threadIdx.x;
    if (i * 4 >= MN) return;
    float4 s = ((const float4*)part)[i];
    for (int sl = 1; sl < nSlice; ++sl) {
        float4 p = ((const float4*)(part + (size_t)sl * MN))[i];
        s.x += p.x; s.y += p.y; s.z += p.z; s.w += p.w;
    }
    int col = (i * 4) % N;
    float v[4] = {s.x, s.y, s.z, s.w};
    #pragma unroll
    for (int e = 0; e < 4; ++e) {
        float t = v[e] * descale + (bias ? bias[col + e] : 0.0f);
        if (relu) t = fmaxf(t, 0.0f);
        v[e] = t;
    }
    if (outF) ((float4*)outF)[i] = *(float4*)v;
    if (outHi) {
        half4v hv, lv;
        #pragma unroll
        for (int e = 0; e < 4; ++e) {
            float sv = v[e] * outScale;
            _Float16 h = (_Float16)sv;
            hv[e] = h;
            lv[e] = (_Float16)(sv - (float)h);
        }
        ((half4v*)outHi)[i] = hv;
        ((half4v*)outLo)[i] = lv;
    }
}

// ---------------------------------------------------------------------------
// Transpose fp32 [R][C] -> scaled f16 hi/lo [C][R]. 32x32 LDS tiles.
// ---------------------------------------------------------------------------
__global__ __launch_bounds__(256)
void transpose_split(const float* __restrict__ src, _Float16* __restrict__ hi,
                     _Float16* __restrict__ lo, float scale, int R, int C)
{
    __shared__ float t[32][33];
    int tx = threadIdx.x & 31, ty = threadIdx.x >> 5;
    int r0 = blockIdx.y * 32, c0 = blockIdx.x * 32;
    #pragma unroll
    for (int p = 0; p < 4; ++p) {
        int r = ty + p * 8;
        t[r][tx] = src[(size_t)(r0 + r) * C + c0 + tx];
    }
    __syncthreads();
    #pragma unroll
    for (int p = 0; p < 4; ++p) {
        int oc = ty + p * 8;
        float v = t[tx][oc] * scale;
        _Float16 h = (_Float16)v;
        size_t o = (size_t)(c0 + oc) * R + r0 + tx;
        hi[o] = h;
        lo[o] = (_Float16)(v - (float)h);
    }
}

// ---------------------------------------------------------------------------
// Normalize codebook rows (fp32 math), emit scaled f16 hi/lo [K][E].
// ---------------------------------------------------------------------------
__global__ __launch_bounds__(256)
void norm_codes(const float* __restrict__ emb, _Float16* __restrict__ cnHi,
                _Float16* __restrict__ cnLo)
{
    int wave = threadIdx.x >> 6;
    int lane = threadIdx.x & 63;
    int c = blockIdx.x * 4 + wave;
    if (c >= KCODE) return;
    const float* er = emb + (size_t)c * EMB;
    float ss = 0.0f;
    #pragma unroll
    for (int k = lane; k < EMB; k += 64) { float v = er[k]; ss += v * v; }
    #pragma unroll
    for (int off = 32; off > 0; off >>= 1) ss += __shfl_down(ss, off, 64);
    ss = __shfl(ss, 0, 64);
    float inv = 1.0f / (sqrtf(ss) + 1e-12f);
    #pragma unroll
    for (int k = lane; k < EMB; k += 64) {
        float v = er[k] * inv * SC_CODE;
        _Float16 h = (_Float16)v;
        cnHi[(size_t)c * EMB + k] = h;
        cnLo[(size_t)c * EMB + k] = (_Float16)(v - (float)h);
    }
}

// ---------------------------------------------------------------------------
// Argmax + fused outputs, one block (256 thr) per row for full gather BW.
// sim[row][c] = p0[row][c] + p1[row][c] (2 split-K partials; positive common
// scale is argmax-invariant). Wave 0 finds argmax (first-index tie-break),
// broadcast via LDS, then ALL 256 threads write onehot, vqfeat, decoded
// (gather of precomputed Dcode[bestI]).
// ---------------------------------------------------------------------------
__global__ __launch_bounds__(256)
void argmax_vq3(const float* __restrict__ part, int MN,
                const float* __restrict__ emb,
                const float* __restrict__ Dcode,
                float* __restrict__ onehot, float* __restrict__ vqfeat,
                float* __restrict__ decoded)
{
    __shared__ int sBest;
    const int row = blockIdx.x;
    const int tid = threadIdx.x;

    if (tid < 64) {
        const float* p0 = part + (size_t)row * KCODE;
        const float* p1 = part + (size_t)MN + (size_t)row * KCODE;
        float bestV = -3.402823466e+38f;
        int   bestI = 0;
        #pragma unroll
        for (int c = tid; c < KCODE; c += 64) {
            float v = p0[c] + p1[c];
            if (v > bestV) { bestV = v; bestI = c; }
        }
        #pragma unroll
        for (int off = 32; off > 0; off >>= 1) {
            float ov = __shfl_down(bestV, off, 64);
            int   oi = __shfl_down(bestI, off, 64);
            if (ov > bestV || (ov == bestV && oi < bestI)) { bestV = ov; bestI = oi; }
        }
        if (tid == 0) sBest = bestI;
    }
    __syncthreads();
    const int bestI = sBest;

    float* oh = onehot + (size_t)row * KCODE;
    oh[tid]       = (tid       == bestI) ? 1.0f : 0.0f;
    oh[tid + 256] = (tid + 256 == bestI) ? 1.0f : 0.0f;

    vqfeat[(size_t)row * EMB + tid] = emb[(size_t)bestI * EMB + tid];

    const float4* sd = (const float4*)(Dcode + (size_t)bestI * FEAT);
    float4* dd = (float4*)(decoded + (size_t)row * FEAT);
    #pragma unroll
    for (int i = tid; i < FEAT / 4; i += 256) dd[i] = sd[i];
}

__global__ __launch_bounds__(256)
void copy_f4(const float* __restrict__ src, float* __restrict__ dst, int n4)
{
    int i = blockIdx.x * 256 + threadIdx.x;
    if (i < n4) ((float4*)dst)[i] = ((const float4*)src)[i];
}

// ---------------------------------------------------------------------------
extern "C" void kernel_launch(void* const* d_in, const int* in_sizes, int n_in,
                              void* d_out, int out_size, void* d_ws, size_t ws_size,
                              hipStream_t stream)
{
    const float* x      = (const float*)d_in[0];
    const float* enc_w1 = (const float*)d_in[1];
    const float* enc_b1 = (const float*)d_in[2];
    const float* enc_w2 = (const float*)d_in[3];
    const float* enc_b2 = (const float*)d_in[4];
    const float* emb    = (const float*)d_in[5];
    const float* dec_w1 = (const float*)d_in[6];
    const float* dec_b1 = (const float*)d_in[7];
    const float* dec_w2 = (const float*)d_in[8];
    const float* dec_b2 = (const float*)d_in[9];

    float* out = (float*)d_out;
    float* out_encoded = out;
    float* out_vqfeat  = out + (size_t)BATCH * EMB;
    float* out_onehot  = out + (size_t)2 * BATCH * EMB;
    float* out_decoded = out + (size_t)2 * BATCH * EMB + (size_t)BATCH * KCODE;
    float* out_emb     = out_decoded + (size_t)BATCH * FEAT;

    // ------- workspace layout (~116 MB) -------
    char* w = (char*)d_ws;
    _Float16* w1T_hi = (_Float16*)w;  w += (size_t)FEAT * MID * 2;
    _Float16* w1T_lo = (_Float16*)w;  w += (size_t)FEAT * MID * 2;
    _Float16* w2T_hi = (_Float16*)w;  w += (size_t)MID * EMB * 2;
    _Float16* w2T_lo = (_Float16*)w;  w += (size_t)MID * EMB * 2;
    _Float16* wd1T_hi= (_Float16*)w;  w += (size_t)MID * EMB * 2;
    _Float16* wd1T_lo= (_Float16*)w;  w += (size_t)MID * EMB * 2;
    _Float16* wd2T_hi= (_Float16*)w;  w += (size_t)FEAT * MID * 2;
    _Float16* wd2T_lo= (_Float16*)w;  w += (size_t)FEAT * MID * 2;
    _Float16* h_hi   = (_Float16*)w;  w += (size_t)BATCH * MID * 2;
    _Float16* h_lo   = (_Float16*)w;  w += (size_t)BATCH * MID * 2;
    _Float16* enc_hi = (_Float16*)w;  w += (size_t)BATCH * EMB * 2;
    _Float16* enc_lo = (_Float16*)w;  w += (size_t)BATCH * EMB * 2;
    _Float16* cn_hi  = (_Float16*)w;  w += (size_t)KCODE * EMB * 2;
    _Float16* cn_lo  = (_Float16*)w;  w += (size_t)KCODE * EMB * 2;
    _Float16* tm_hi  = (_Float16*)w;  w += (size_t)KCODE * MID * 2;
    _Float16* tm_lo  = (_Float16*)w;  w += (size_t)KCODE * MID * 2;
    float*    Dc     = (float*)w;     w += (size_t)KCODE * FEAT * 4;
    float*    scr    = (float*)w;     w += (size_t)4 * BATCH * MID * 4;  // 64 MB, reused

    // --- prep: weight transposes/splits, codebook norm, emb passthrough ---
    transpose_split<<<dim3(MID / 32, FEAT / 32), dim3(256), 0, stream>>>(
        enc_w1, w1T_hi, w1T_lo, SC_W, FEAT, MID);
    transpose_split<<<dim3(EMB / 32, MID / 32), dim3(256), 0, stream>>>(
        enc_w2, w2T_hi, w2T_lo, SC_W, MID, EMB);
    transpose_split<<<dim3(MID / 32, EMB / 32), dim3(256), 0, stream>>>(
        dec_w1, wd1T_hi, wd1T_lo, SC_W, EMB, MID);
    transpose_split<<<dim3(FEAT / 32, MID / 32), dim3(256), 0, stream>>>(
        dec_w2, wd2T_hi, wd2T_lo, SC_W, MID, FEAT);
    norm_codes<<<dim3(KCODE / 4), dim3(256), 0, stream>>>(emb, cn_hi, cn_lo);
    copy_f4<<<dim3((KCODE * EMB / 4 + 255) / 256), dim3(256), 0, stream>>>(
        emb, out_emb, KCODE * EMB / 4);

    // --- decoder on codebook only (512 distinct rows), 1-term f16 ---
    gemm_sk<1, 1><<<dim3(KCODE / 128, KCODE / 128), dim3(256), 0, stream>>>(
        emb, nullptr, nullptr, wd1T_hi, wd1T_lo, SC_EMB,
        nullptr, dec_b1, DS_D1, 1, nullptr, tm_hi, tm_lo, SC_TM,
        KCODE, MID, EMB, 0, 0, 0);
    gemm_sk<1, 0><<<dim3(FEAT / 128, KCODE / 128), dim3(256), 0, stream>>>(
        nullptr, tm_hi, tm_lo, wd2T_hi, wd2T_lo, 0.0f,
        nullptr, dec_b2, DS_D2, 1, Dc, nullptr, nullptr, 0.0f,
        KCODE, FEAT, MID, 0, 0, 0);

    // --- G1: x @ w1 partials; split-K=2, 512 blocks (2/CU, single round),
    // swizzled, AF32=1 in-loop split, counted-vmcnt schedule
    gemm_sk<3, 1><<<dim3(512), dim3(256), 0, stream>>>(
        x, nullptr, nullptr, w1T_hi, w1T_lo, SC_X,
        scr, nullptr, 0.0f, 0, nullptr, nullptr, nullptr, 0.0f,
        BATCH, MID, FEAT, 1, 2, 1);
    // red1: h = relu(sum * DS_G1 + b1) -> h hi/lo
    reduce_sk<<<dim3(BATCH * MID / 4 / 256), dim3(256), 0, stream>>>(
        scr, 2, BATCH * MID, MID, enc_b1, DS_G1, 1,
        nullptr, h_hi, h_lo, SC_H);

    // --- G2: h @ w2 partials; split-K=4, 512 blocks, swizzled
    gemm_sk<3, 0><<<dim3(512), dim3(256), 0, stream>>>(
        nullptr, h_hi, h_lo, w2T_hi, w2T_lo, 0.0f,
        scr, nullptr, 0.0f, 0, nullptr, nullptr, nullptr, 0.0f,
        BATCH, EMB, MID, 2, 1, 1);
    // red2: encoded = sum * DS_G2 + b2 -> fp32 out + enc hi/lo
    reduce_sk<<<dim3(BATCH * EMB / 4 / 256), dim3(256), 0, stream>>>(
        scr, 4, BATCH * EMB, EMB, enc_b2, DS_G2, 0,
        out_encoded, enc_hi, enc_lo, SC_ENC);

    // --- G3: enc @ cn^T partials; split-K=2, 512 blocks, swizzled
    gemm_sk<3, 0><<<dim3(512), dim3(256), 0, stream>>>(
        nullptr, enc_hi, enc_lo, cn_hi, cn_lo, 0.0f,
        scr, nullptr, 0.0f, 0, nullptr, nullptr, nullptr, 0.0f,
        BATCH, KCODE, EMB, 1, 2, 1);
    // --- argmax over (p0+p1): one-hot, vq_feat, fused decoded gather
    argmax_vq3<<<dim3(BATCH), dim3(256), 0, stream>>>(
        scr, BATCH * KCODE, emb, Dc, out_onehot, out_vqfeat, out_decoded);
}

// Round 4
// 465.380 us; speedup vs baseline: 1.1774x; 1.0464x over previous
//
#include <hip/hip_runtime.h>

#define BATCH 8192
#define FEAT  4096
#define MID   512
#define EMB   256
#define KCODE 512

typedef _Float16 half8 __attribute__((ext_vector_type(8)));
typedef _Float16 half4v __attribute__((ext_vector_type(4)));
typedef float floatx4 __attribute__((ext_vector_type(4)));

// Power-of-2 scales; descaled exactly in epilogues/reduces.
#define SC_X    512.0f
#define SC_W    4096.0f
#define SC_H    512.0f
#define SC_ENC  4096.0f
#define SC_CODE 4096.0f
#define SC_EMB  4096.0f
#define SC_TM   512.0f
#define DS_G1   (1.0f / (SC_X   * SC_W))
#define DS_G2   (1.0f / (SC_H   * SC_W))
#define DS_D1   (1.0f / (SC_EMB * SC_W))
#define DS_D2   (1.0f / (SC_TM  * SC_W))

#define GLD16(gp, lp)                                                          \
    __builtin_amdgcn_global_load_lds(                                          \
        (const __attribute__((address_space(1))) void*)(gp),                   \
        (__attribute__((address_space(3))) void*)(lp), 16, 0, 0)

// ---------------------------------------------------------------------------
// Split-K MFMA GEMM, 128x128 tile, BK=32, 4 waves (2x2 of 64x64).
// C = A @ B^T (B pre-split/scaled f16 hi/lo, TRANSPOSED [N][K]).
// NT=3: hi*hi + hi*lo + lo*hi (fp32-equivalent). NT=1: hi only.
// ASRC=0: A pre-split hi/lo planes via GLD16.
// ASRC=1: A fp32, scaled+split in-register (loads early, cvt post-MFMA).
// ASRC=2: A = relu((scr0+scr1)*redDS + redBias[k]) * aScale, split in-register
//         (fuses the split-K reduce of the PREVIOUS gemm into this staging;
//         arithmetic identical to reduce_sk's, so numerics are unchanged).
//
// Counted-vmcnt schedule (raw barriers; vmcnt(0) only on the last iter):
//   iter t: issue staging (A regs first, then B GLD16s) -> buf[nxt]
//           s_waitcnt vmcnt(PFW)  <- retires only iter t-1's B GLD16s
//           s_barrier             <- buf[cur] fully staged, mine in flight
//           ds_read buf[cur]; MFMA (compiler-managed lgkm deps)
//           (ASRC>0: cvt regs -> ds_write buf[nxt]; lgkmcnt(0))
//           s_barrier             <- buf[cur] readers done
// PFW = #vmem ops issued this iter (t-1's A-regs already retired at its cvt).
//
// If partOut != null: raw fp32 accumulators to partOut[ks*M*N + ...].
// Else: final epilogue (descale, bias, relu, fp32 / hi-lo out).
// swz: 1-D grid, b -> {m_lo=b&7, ks, n, m_hi}; n/k-peers of an M-stripe share
// b%8 (same XCD) for L2-shared A; gridM%8==0 required.
// ---------------------------------------------------------------------------
template<int NT, int ASRC>
__global__ __launch_bounds__(256)
void gemm_sk(const float* __restrict__ Af32,
             const _Float16* __restrict__ Ahg, const _Float16* __restrict__ Alg,
             const _Float16* __restrict__ BTh, const _Float16* __restrict__ BTl,
             float aScale,
             const float* __restrict__ redBias, float redDS, int redMN,
             float* __restrict__ partOut,
             const float* __restrict__ bias, float descale, int relu,
             float* __restrict__ outF, _Float16* __restrict__ outHi,
             _Float16* __restrict__ outLo, float outScale,
             int M, int N, int K, int lgK, int lgN, int swz)
{
    __shared__ _Float16 AhS[2][128 * 32];
    __shared__ _Float16 BhS[2][128 * 32];
    __shared__ _Float16 AlS[NT == 3 ? 2 : 1][NT == 3 ? 128 * 32 : 8];
    __shared__ _Float16 BlS[NT == 3 ? 2 : 1][NT == 3 ? 128 * 32 : 8];

    const int tid  = threadIdx.x;
    const int lane = tid & 63;
    const int wave = tid >> 6;
    const int wm = wave >> 1, wn = wave & 1;
    const int l15  = lane & 15;
    const int quad = lane >> 4;
    const int q8   = quad * 8;

    int bm, bn, ks;
    if (swz) {
        int b = blockIdx.x;
        int mlo = b & 7;
        ks = (b >> 3) & ((1 << lgK) - 1);
        bn = (b >> (3 + lgK)) & ((1 << lgN) - 1);
        bm = ((b >> (3 + lgK + lgN)) << 3) | mlo;
    } else { bm = blockIdx.y; bn = blockIdx.x; ks = 0; }
    const int row0 = bm * 128, col0 = bn * 128;
    const int Kslice = K >> lgK;
    const int k0 = ks * Kslice;

    // GLD16 staging coords (64 rows per call; two calls = 128 rows)
    const int sr4 = tid >> 2;
    const int sc4 = (tid & 3) * 8;
    const size_t aB0 = (size_t)(row0 + sr4) * K + sc4;
    const size_t aB1 = (size_t)(row0 + 64 + sr4) * K + sc4;
    const size_t bB0 = (size_t)(col0 + sr4) * K + sc4;
    const size_t bB1 = (size_t)(col0 + 64 + sr4) * K + sc4;
    const int l0 = tid * 8, l1 = 2048 + tid * 8;

    // reg-staging coords (one pass: 256 threads x 16 elems = 128x32)
    const int sr2 = tid >> 1;
    const int sk2 = (tid & 1) * 16;
    const size_t aOff2 = (size_t)(row0 + sr2) * K + sk2;
    const int lA = sr2 * 32 + sk2;

    floatx4 acc[4][4] = {};

    // ASRC==1: 16 fp32 -> scaled f16 hi/lo -> LDS buffer s
    auto cvtA1 = [&](int s, float4 f0, float4 f1, float4 f2, float4 f3) {
        float fv[16] = {f0.x,f0.y,f0.z,f0.w, f1.x,f1.y,f1.z,f1.w,
                        f2.x,f2.y,f2.z,f2.w, f3.x,f3.y,f3.z,f3.w};
        half8 hv0, hv1, lv0, lv1;
        #pragma unroll
        for (int e = 0; e < 8; ++e) {
            float v = fv[e] * aScale;
            _Float16 h = (_Float16)v;
            hv0[e] = h; lv0[e] = (_Float16)(v - (float)h);
        }
        #pragma unroll
        for (int e = 0; e < 8; ++e) {
            float v = fv[8 + e] * aScale;
            _Float16 h = (_Float16)v;
            hv1[e] = h; lv1[e] = (_Float16)(v - (float)h);
        }
        *(half8*)&AhS[s][lA] = hv0; *(half8*)&AhS[s][lA + 8] = hv1;
        if (NT == 3) {
            *(half8*)&AlS[s][lA] = lv0; *(half8*)&AlS[s][lA + 8] = lv1;
        }
    };

    // ASRC==2: relu((s0+s1)*redDS + bias) * aScale -> split -> LDS buffer s
    auto cvtA2 = [&](int s,
                     float4 A0, float4 A1, float4 A2, float4 A3,
                     float4 C0, float4 C1, float4 C2, float4 C3,
                     float4 B0, float4 B1, float4 B2, float4 B3) {
        float sv[16] = {A0.x+C0.x, A0.y+C0.y, A0.z+C0.z, A0.w+C0.w,
                        A1.x+C1.x, A1.y+C1.y, A1.z+C1.z, A1.w+C1.w,
                        A2.x+C2.x, A2.y+C2.y, A2.z+C2.z, A2.w+C2.w,
                        A3.x+C3.x, A3.y+C3.y, A3.z+C3.z, A3.w+C3.w};
        float bv[16] = {B0.x,B0.y,B0.z,B0.w, B1.x,B1.y,B1.z,B1.w,
                        B2.x,B2.y,B2.z,B2.w, B3.x,B3.y,B3.z,B3.w};
        half8 hv0, hv1, lv0, lv1;
        #pragma unroll
        for (int e = 0; e < 8; ++e) {
            float t = sv[e] * redDS + bv[e];
            t = fmaxf(t, 0.0f);
            float v = t * aScale;
            _Float16 h = (_Float16)v;
            hv0[e] = h; lv0[e] = (_Float16)(v - (float)h);
        }
        #pragma unroll
        for (int e = 0; e < 8; ++e) {
            float t = sv[8 + e] * redDS + bv[8 + e];
            t = fmaxf(t, 0.0f);
            float v = t * aScale;
            _Float16 h = (_Float16)v;
            hv1[e] = h; lv1[e] = (_Float16)(v - (float)h);
        }
        *(half8*)&AhS[s][lA] = hv0; *(half8*)&AhS[s][lA + 8] = hv1;
        *(half8*)&AlS[s][lA] = lv0; *(half8*)&AlS[s][lA + 8] = lv1;
    };

    const int Ksteps = Kslice >> 5;

    // vmem ops issued per prefetch iter (what stays in flight at barrier1)
    constexpr int PFW = (ASRC == 2) ? 16 : (NT == 3 ? 8 : (ASRC == 1 ? 6 : 4));

    // ---- prologue: stage step 0 into buffer 0 ----
    {
        if constexpr (ASRC == 0) {
            GLD16(Ahg + aB0 + k0, &AhS[0][l0]);
            GLD16(Ahg + aB1 + k0, &AhS[0][l1]);
            if (NT == 3) {
                GLD16(Alg + aB0 + k0, &AlS[0][l0]);
                GLD16(Alg + aB1 + k0, &AlS[0][l1]);
            }
        }
        GLD16(BTh + bB0 + k0, &BhS[0][l0]);
        GLD16(BTh + bB1 + k0, &BhS[0][l1]);
        if (NT == 3) {
            GLD16(BTl + bB0 + k0, &BlS[0][l0]);
            GLD16(BTl + bB1 + k0, &BlS[0][l1]);
        }
        if constexpr (ASRC == 1) {
            const float* p = Af32 + aOff2 + k0;
            float4 f0 = *(const float4*)(p);
            float4 f1 = *(const float4*)(p + 4);
            float4 f2 = *(const float4*)(p + 8);
            float4 f3 = *(const float4*)(p + 12);
            cvtA1(0, f0, f1, f2, f3);
            asm volatile("s_waitcnt lgkmcnt(0)" ::: "memory");
        } else if constexpr (ASRC == 2) {
            const float* p0 = Af32 + aOff2 + k0;
            const float* p1 = p0 + redMN;
            const float* pb = redBias + k0 + sk2;
            float4 A0 = ((const float4*)p0)[0], A1 = ((const float4*)p0)[1];
            float4 A2 = ((const float4*)p0)[2], A3 = ((const float4*)p0)[3];
            float4 C0 = ((const float4*)p1)[0], C1 = ((const float4*)p1)[1];
            float4 C2 = ((const float4*)p1)[2], C3 = ((const float4*)p1)[3];
            float4 B0 = ((const float4*)pb)[0], B1 = ((const float4*)pb)[1];
            float4 B2 = ((const float4*)pb)[2], B3 = ((const float4*)pb)[3];
            cvtA2(0, A0,A1,A2,A3, C0,C1,C2,C3, B0,B1,B2,B3);
            asm volatile("s_waitcnt lgkmcnt(0)" ::: "memory");
        }
    }

    for (int it = 0; it < Ksteps; ++it) {
        const int cur = it & 1, nxt = cur ^ 1;
        const bool pf = (it + 1) < Ksteps;
        float4 f0, f1, f2, f3;                                   // ASRC==1
        float4 A0, A1, A2, A3, C0, C1, C2, C3, B0, B1, B2, B3;   // ASRC==2
        // ---- issue next-tile staging (stays in flight through barrier1) ----
        if (pf) {
            const int kk = k0 + (it + 1) * 32;
            if constexpr (ASRC == 0) {
                GLD16(Ahg + aB0 + kk, &AhS[nxt][l0]);
                GLD16(Ahg + aB1 + kk, &AhS[nxt][l1]);
                if (NT == 3) {
                    GLD16(Alg + aB0 + kk, &AlS[nxt][l0]);
                    GLD16(Alg + aB1 + kk, &AlS[nxt][l1]);
                }
            } else if constexpr (ASRC == 1) {
                const float* p = Af32 + aOff2 + kk;
                f0 = *(const float4*)(p);
                f1 = *(const float4*)(p + 4);
                f2 = *(const float4*)(p + 8);
                f3 = *(const float4*)(p + 12);
            } else {
                const float* p0 = Af32 + aOff2 + kk;
                const float* p1 = p0 + redMN;
                const float* pb = redBias + kk + sk2;
                A0 = ((const float4*)p0)[0]; A1 = ((const float4*)p0)[1];
                A2 = ((const float4*)p0)[2]; A3 = ((const float4*)p0)[3];
                C0 = ((const float4*)p1)[0]; C1 = ((const float4*)p1)[1];
                C2 = ((const float4*)p1)[2]; C3 = ((const float4*)p1)[3];
                B0 = ((const float4*)pb)[0]; B1 = ((const float4*)pb)[1];
                B2 = ((const float4*)pb)[2]; B3 = ((const float4*)pb)[3];
            }
            GLD16(BTh + bB0 + kk, &BhS[nxt][l0]);
            GLD16(BTh + bB1 + kk, &BhS[nxt][l1]);
            if (NT == 3) {
                GLD16(BTl + bB0 + kk, &BlS[nxt][l0]);
                GLD16(BTl + bB1 + kk, &BlS[nxt][l1]);
            }
            // counted wait: only the PREVIOUS iter's staging must have landed
            asm volatile("s_waitcnt vmcnt(%0)" :: "i"(PFW) : "memory");
        } else {
            asm volatile("s_waitcnt vmcnt(0)" ::: "memory");
        }
        __builtin_amdgcn_s_barrier();   // raw: this iter's loads stay in flight

        // ---- compute on current buffer ----
        half8 ah[4], al4[4], bh[4], bl4[4];
        #pragma unroll
        for (int i = 0; i < 4; ++i) {
            int ra = (wm * 64 + i * 16 + l15) * 32 + q8;
            int rb = (wn * 64 + i * 16 + l15) * 32 + q8;
            ah[i] = *(const half8*)&AhS[cur][ra];
            bh[i] = *(const half8*)&BhS[cur][rb];
            if (NT == 3) {
                al4[i] = *(const half8*)&AlS[cur][ra];
                bl4[i] = *(const half8*)&BlS[cur][rb];
            }
        }
        #pragma unroll
        for (int i = 0; i < 4; ++i)
            #pragma unroll
            for (int j = 0; j < 4; ++j) {
                acc[i][j] = __builtin_amdgcn_mfma_f32_16x16x32_f16(ah[i], bh[j], acc[i][j], 0, 0, 0);
                if (NT == 3) {
                    acc[i][j] = __builtin_amdgcn_mfma_f32_16x16x32_f16(ah[i],  bl4[j], acc[i][j], 0, 0, 0);
                    acc[i][j] = __builtin_amdgcn_mfma_f32_16x16x32_f16(al4[i], bh[j],  acc[i][j], 0, 0, 0);
                }
            }
        // ---- commit: convert A regs (their loads waited here, post-MFMA) ----
        if constexpr (ASRC == 1) {
            if (pf) {
                cvtA1(nxt, f0, f1, f2, f3);
                asm volatile("s_waitcnt lgkmcnt(0)" ::: "memory");
            }
        } else if constexpr (ASRC == 2) {
            if (pf) {
                cvtA2(nxt, A0,A1,A2,A3, C0,C1,C2,C3, B0,B1,B2,B3);
                asm volatile("s_waitcnt lgkmcnt(0)" ::: "memory");
            }
        }
        __builtin_amdgcn_s_barrier();   // buf[cur] readers done
    }

    // Epilogue. C/D layout: col = lane&15, row = quad*4 + reg (verified m89).
    if (partOut) {
        float* po = partOut + (size_t)ks * M * N;
        #pragma unroll
        for (int j = 0; j < 4; ++j) {
            int col = col0 + wn * 64 + j * 16 + l15;
            #pragma unroll
            for (int i = 0; i < 4; ++i)
                #pragma unroll
                for (int t = 0; t < 4; ++t) {
                    int r = row0 + wm * 64 + i * 16 + quad * 4 + t;
                    po[(size_t)r * N + col] = acc[i][j][t];
                }
        }
    } else {
        #pragma unroll
        for (int j = 0; j < 4; ++j) {
            int col = col0 + wn * 64 + j * 16 + l15;
            float bcol = bias ? bias[col] : 0.0f;
            #pragma unroll
            for (int i = 0; i < 4; ++i)
                #pragma unroll
                for (int t = 0; t < 4; ++t) {
                    int r = row0 + wm * 64 + i * 16 + quad * 4 + t;
                    float v = acc[i][j][t] * descale + bcol;
                    if (relu) v = fmaxf(v, 0.0f);
                    size_t o = (size_t)r * N + col;
                    if (outF) outF[o] = v;
                    if (outHi) {
                        float sv = v * outScale;
                        _Float16 h = (_Float16)sv;
                        outHi[o] = h;
                        outLo[o] = (_Float16)(sv - (float)h);
                    }
                }
        }
    }
}

// ---------------------------------------------------------------------------
// Split-K reduce: out = relu( (sum_s part[s]) * descale + bias ), emitting
// fp32 and/or scaled f16 hi/lo. float4 per thread.
// ---------------------------------------------------------------------------
__global__ __launch_bounds__(256)
void reduce_sk(const float* __restrict__ part, int nSlice, int MN, int N,
               const float* __restrict__ bias, float descale, int relu,
               float* __restrict__ outF, _Float16* __restrict__ outHi,
               _Float16* __restrict__ outLo, float outScale)
{
    int i = blockIdx.x * 256 + threadIdx.x;
    if (i * 4 >= MN) return;
    float4 s = ((const float4*)part)[i];
    for (int sl = 1; sl < nSlice; ++sl) {
        float4 p = ((const float4*)(part + (size_t)sl * MN))[i];
        s.x += p.x; s.y += p.y; s.z += p.z; s.w += p.w;
    }
    int col = (i * 4) % N;
    float v[4] = {s.x, s.y, s.z, s.w};
    #pragma unroll
    for (int e = 0; e < 4; ++e) {
        float t = v[e] * descale + (bias ? bias[col + e] : 0.0f);
        if (relu) t = fmaxf(t, 0.0f);
        v[e] = t;
    }
    if (outF) ((float4*)outF)[i] = *(float4*)v;
    if (outHi) {
        half4v hv, lv;
        #pragma unroll
        for (int e = 0; e < 4; ++e) {
            float sv = v[e] * outScale;
            _Float16 h = (_Float16)sv;
            hv[e] = h;
            lv[e] = (_Float16)(sv - (float)h);
        }
        ((half4v*)outHi)[i] = hv;
        ((half4v*)outLo)[i] = lv;
    }
}

// ---------------------------------------------------------------------------
// Transpose fp32 [R][C] -> scaled f16 hi/lo [C][R]. 32x32 LDS tile (passed in).
// ---------------------------------------------------------------------------
__device__ __forceinline__ void transpose_body(
    float (*t)[33],
    const float* __restrict__ src, _Float16* __restrict__ hi,
    _Float16* __restrict__ lo, float scale, int R, int C, int bx, int by)
{
    int tx = threadIdx.x & 31, ty = threadIdx.x >> 5;
    int r0 = by * 32, c0 = bx * 32;
    #pragma unroll
    for (int p = 0; p < 4; ++p) {
        int r = ty + p * 8;
        t[r][tx] = src[(size_t)(r0 + r) * C + c0 + tx];
    }
    __syncthreads();
    #pragma unroll
    for (int p = 0; p < 4; ++p) {
        int oc = ty + p * 8;
        float v = t[tx][oc] * scale;
        _Float16 h = (_Float16)v;
        size_t o = (size_t)(c0 + oc) * R + r0 + tx;
        hi[o] = h;
        lo[o] = (_Float16)(v - (float)h);
    }
}

// ---------------------------------------------------------------------------
// All prep work in ONE launch, blocks partitioned by role:
//   [0,2048):    enc_w1 transpose-split  (16 x 128 tiles)
//   [2048,2176): enc_w2 transpose-split  (8 x 16)
//   [2176,2304): dec_w1 transpose-split  (16 x 8)
//   [2304,4352): dec_w2 transpose-split  (128 x 16)
//   [4352,4480): codebook row-normalize -> cn hi/lo
//   [4480,4608): emb passthrough copy
// ---------------------------------------------------------------------------
__global__ __launch_bounds__(256)
void prep_fused(const float* __restrict__ enc_w1, const float* __restrict__ enc_w2,
                const float* __restrict__ dec_w1, const float* __restrict__ dec_w2,
                const float* __restrict__ emb,
                _Float16* __restrict__ w1T_hi, _Float16* __restrict__ w1T_lo,
                _Float16* __restrict__ w2T_hi, _Float16* __restrict__ w2T_lo,
                _Float16* __restrict__ wd1T_hi, _Float16* __restrict__ wd1T_lo,
                _Float16* __restrict__ wd2T_hi, _Float16* __restrict__ wd2T_lo,
                _Float16* __restrict__ cnHi, _Float16* __restrict__ cnLo,
                float* __restrict__ out_emb)
{
    __shared__ float t[32][33];
    const int b = blockIdx.x;
    if (b < 2048) {
        transpose_body(t, enc_w1, w1T_hi, w1T_lo, SC_W, FEAT, MID, b & 15, b >> 4);
    } else if (b < 2176) {
        int bb = b - 2048;
        transpose_body(t, enc_w2, w2T_hi, w2T_lo, SC_W, MID, EMB, bb & 7, bb >> 3);
    } else if (b < 2304) {
        int bb = b - 2176;
        transpose_body(t, dec_w1, wd1T_hi, wd1T_lo, SC_W, EMB, MID, bb & 15, bb >> 4);
    } else if (b < 4352) {
        int bb = b - 2304;
        transpose_body(t, dec_w2, wd2T_hi, wd2T_lo, SC_W, MID, FEAT, bb & 127, bb >> 7);
    } else if (b < 4480) {
        int wv = threadIdx.x >> 6, lane = threadIdx.x & 63;
        int c = (b - 4352) * 4 + wv;
        const float* er = emb + (size_t)c * EMB;
        float ss = 0.0f;
        #pragma unroll
        for (int k = lane; k < EMB; k += 64) { float v = er[k]; ss += v * v; }
        #pragma unroll
        for (int off = 32; off > 0; off >>= 1) ss += __shfl_down(ss, off, 64);
        ss = __shfl(ss, 0, 64);
        float inv = 1.0f / (sqrtf(ss) + 1e-12f);
        #pragma unroll
        for (int k = lane; k < EMB; k += 64) {
            float v = er[k] * inv * SC_CODE;
            _Float16 h = (_Float16)v;
            cnHi[(size_t)c * EMB + k] = h;
            cnLo[(size_t)c * EMB + k] = (_Float16)(v - (float)h);
        }
    } else {
        int i = (b - 4480) * 256 + threadIdx.x;
        ((float4*)out_emb)[i] = ((const float4*)emb)[i];
    }
}

// ---------------------------------------------------------------------------
// Argmax + fused outputs, one block (256 thr) per row for full gather BW.
// sim[row][c] = p0[row][c] + p1[row][c] (2 split-K partials; positive common
// scale is argmax-invariant). Wave 0 finds argmax (first-index tie-break),
// broadcast via LDS, then ALL 256 threads write onehot, vqfeat, decoded
// (gather of precomputed Dcode[bestI]).
// ---------------------------------------------------------------------------
__global__ __launch_bounds__(256)
void argmax_vq3(const float* __restrict__ part, int MN,
                const float* __restrict__ emb,
                const float* __restrict__ Dcode,
                float* __restrict__ onehot, float* __restrict__ vqfeat,
                float* __restrict__ decoded)
{
    __shared__ int sBest;
    const int row = blockIdx.x;
    const int tid = threadIdx.x;

    if (tid < 64) {
        const float* p0 = part + (size_t)row * KCODE;
        const float* p1 = part + (size_t)MN + (size_t)row * KCODE;
        float bestV = -3.402823466e+38f;
        int   bestI = 0;
        #pragma unroll
        for (int c = tid; c < KCODE; c += 64) {
            float v = p0[c] + p1[c];
            if (v > bestV) { bestV = v; bestI = c; }
        }
        #pragma unroll
        for (int off = 32; off > 0; off >>= 1) {
            float ov = __shfl_down(bestV, off, 64);
            int   oi = __shfl_down(bestI, off, 64);
            if (ov > bestV || (ov == bestV && oi < bestI)) { bestV = ov; bestI = oi; }
        }
        if (tid == 0) sBest = bestI;
    }
    __syncthreads();
    const int bestI = sBest;

    float* oh = onehot + (size_t)row * KCODE;
    oh[tid]       = (tid       == bestI) ? 1.0f : 0.0f;
    oh[tid + 256] = (tid + 256 == bestI) ? 1.0f : 0.0f;

    vqfeat[(size_t)row * EMB + tid] = emb[(size_t)bestI * EMB + tid];

    const float4* sd = (const float4*)(Dcode + (size_t)bestI * FEAT);
    float4* dd = (float4*)(decoded + (size_t)row * FEAT);
    #pragma unroll
    for (int i = tid; i < FEAT / 4; i += 256) dd[i] = sd[i];
}

// ---------------------------------------------------------------------------
extern "C" void kernel_launch(void* const* d_in, const int* in_sizes, int n_in,
                              void* d_out, int out_size, void* d_ws, size_t ws_size,
                              hipStream_t stream)
{
    const float* x      = (const float*)d_in[0];
    const float* enc_w1 = (const float*)d_in[1];
    const float* enc_b1 = (const float*)d_in[2];
    const float* enc_w2 = (const float*)d_in[3];
    const float* enc_b2 = (const float*)d_in[4];
    const float* emb    = (const float*)d_in[5];
    const float* dec_w1 = (const float*)d_in[6];
    const float* dec_b1 = (const float*)d_in[7];
    const float* dec_w2 = (const float*)d_in[8];
    const float* dec_b2 = (const float*)d_in[9];

    float* out = (float*)d_out;
    float* out_encoded = out;
    float* out_vqfeat  = out + (size_t)BATCH * EMB;
    float* out_onehot  = out + (size_t)2 * BATCH * EMB;
    float* out_decoded = out + (size_t)2 * BATCH * EMB + (size_t)BATCH * KCODE;
    float* out_emb     = out_decoded + (size_t)BATCH * FEAT;

    // ------- workspace layout (~102 MB) -------
    char* w = (char*)d_ws;
    _Float16* w1T_hi = (_Float16*)w;  w += (size_t)FEAT * MID * 2;
    _Float16* w1T_lo = (_Float16*)w;  w += (size_t)FEAT * MID * 2;
    _Float16* w2T_hi = (_Float16*)w;  w += (size_t)MID * EMB * 2;
    _Float16* w2T_lo = (_Float16*)w;  w += (size_t)MID * EMB * 2;
    _Float16* wd1T_hi= (_Float16*)w;  w += (size_t)MID * EMB * 2;
    _Float16* wd1T_lo= (_Float16*)w;  w += (size_t)MID * EMB * 2;
    _Float16* wd2T_hi= (_Float16*)w;  w += (size_t)FEAT * MID * 2;
    _Float16* wd2T_lo= (_Float16*)w;  w += (size_t)FEAT * MID * 2;
    _Float16* enc_hi = (_Float16*)w;  w += (size_t)BATCH * EMB * 2;
    _Float16* enc_lo = (_Float16*)w;  w += (size_t)BATCH * EMB * 2;
    _Float16* cn_hi  = (_Float16*)w;  w += (size_t)KCODE * EMB * 2;
    _Float16* cn_lo  = (_Float16*)w;  w += (size_t)KCODE * EMB * 2;
    _Float16* tm_hi  = (_Float16*)w;  w += (size_t)KCODE * MID * 2;
    _Float16* tm_lo  = (_Float16*)w;  w += (size_t)KCODE * MID * 2;
    float*    Dc     = (float*)w;     w += (size_t)KCODE * FEAT * 4;
    float*    scr    = (float*)w;     w += (size_t)4 * BATCH * MID * 4;  // 67 MB, reused
    // G2's split-K partials live in the upper half of scr (G1 uses 2 slices =
    // lower half; 4*BATCH*EMB == 2*BATCH*MID floats fits the upper half).
    float*    scr2   = scr + (size_t)2 * BATCH * MID;

    // --- prep: ONE launch (4 transpose-splits + codebook norm + emb copy)
    prep_fused<<<dim3(4608), dim3(256), 0, stream>>>(
        enc_w1, enc_w2, dec_w1, dec_w2, emb,
        w1T_hi, w1T_lo, w2T_hi, w2T_lo, wd1T_hi, wd1T_lo, wd2T_hi, wd2T_lo,
        cn_hi, cn_lo, out_emb);

    // --- decoder on codebook only (512 distinct rows), 1-term f16 ---
    gemm_sk<1, 1><<<dim3(KCODE / 128, KCODE / 128), dim3(256), 0, stream>>>(
        emb, nullptr, nullptr, wd1T_hi, wd1T_lo, SC_EMB,
        nullptr, 0.0f, 0,
        nullptr, dec_b1, DS_D1, 1, nullptr, tm_hi, tm_lo, SC_TM,
        KCODE, MID, EMB, 0, 0, 0);
    gemm_sk<1, 0><<<dim3(FEAT / 128, KCODE / 128), dim3(256), 0, stream>>>(
        nullptr, tm_hi, tm_lo, wd2T_hi, wd2T_lo, 0.0f,
        nullptr, 0.0f, 0,
        nullptr, dec_b2, DS_D2, 1, Dc, nullptr, nullptr, 0.0f,
        KCODE, FEAT, MID, 0, 0, 0);

    // --- G1: x @ w1 partials; split-K=2, 512 blocks (2/CU), swizzled,
    // fp32 A split in-register
    gemm_sk<3, 1><<<dim3(512), dim3(256), 0, stream>>>(
        x, nullptr, nullptr, w1T_hi, w1T_lo, SC_X,
        nullptr, 0.0f, 0,
        scr, nullptr, 0.0f, 0, nullptr, nullptr, nullptr, 0.0f,
        BATCH, MID, FEAT, 1, 2, 1);

    // --- G2: h @ w2 partials; split-K=4, 512 blocks, swizzled.
    // A-staging FUSES red1: h = relu((scr0+scr1)*DS_G1 + b1) on the fly.
    gemm_sk<3, 2><<<dim3(512), dim3(256), 0, stream>>>(
        scr, nullptr, nullptr, w2T_hi, w2T_lo, SC_H,
        enc_b1, DS_G1, BATCH * MID,
        scr2, nullptr, 0.0f, 0, nullptr, nullptr, nullptr, 0.0f,
        BATCH, EMB, MID, 2, 1, 1);
    // red2: encoded = sum * DS_G2 + b2 -> fp32 out + enc hi/lo
    reduce_sk<<<dim3(BATCH * EMB / 4 / 256), dim3(256), 0, stream>>>(
        scr2, 4, BATCH * EMB, EMB, enc_b2, DS_G2, 0,
        out_encoded, enc_hi, enc_lo, SC_ENC);

    // --- G3: enc @ cn^T partials; split-K=2, 512 blocks, swizzled
    // (partials overwrite G1's dead slices at scr base)
    gemm_sk<3, 0><<<dim3(512), dim3(256), 0, stream>>>(
        nullptr, enc_hi, enc_lo, cn_hi, cn_lo, 0.0f,
        nullptr, 0.0f, 0,
        scr, nullptr, 0.0f, 0, nullptr, nullptr, nullptr, 0.0f,
        BATCH, KCODE, EMB, 1, 2, 1);
    // --- argmax over (p0+p1): one-hot, vq_feat, fused decoded gather
    argmax_vq3<<<dim3(BATCH), dim3(256), 0, stream>>>(
        scr, BATCH * KCODE, emb, Dc, out_onehot, out_vqfeat, out_decoded);
}

// Round 5
// 457.948 us; speedup vs baseline: 1.1965x; 1.0162x over previous
//
#include <hip/hip_runtime.h>

#define BATCH 8192
#define FEAT  4096
#define MID   512
#define EMB   256
#define KCODE 512

typedef _Float16 half8 __attribute__((ext_vector_type(8)));
typedef _Float16 half4v __attribute__((ext_vector_type(4)));
typedef float floatx4 __attribute__((ext_vector_type(4)));

// Power-of-2 scales; descaled exactly in epilogues/reduces.
#define SC_X    512.0f
#define SC_W    4096.0f
#define SC_H    512.0f
#define SC_ENC  4096.0f
#define SC_CODE 4096.0f
#define SC_EMB  4096.0f
#define SC_TM   512.0f
#define DS_G1   (1.0f / (SC_X   * SC_W))
#define DS_G2   (1.0f / (SC_H   * SC_W))
#define DS_D1   (1.0f / (SC_EMB * SC_W))
#define DS_D2   (1.0f / (SC_TM  * SC_W))

#define GLD16(gp, lp)                                                          \
    __builtin_amdgcn_global_load_lds(                                          \
        (const __attribute__((address_space(1))) void*)(gp),                   \
        (__attribute__((address_space(3))) void*)(lp), 16, 0, 0)

// ---------------------------------------------------------------------------
// G1-dedicated kernel: C = x @ w1 (split-K=2 partials), fp32-equivalent via
// f16 hi/lo 3-term. 256x128 tile, BK=32, 8 waves (2M x 4N), grid 256 = 1/CU.
//  - LDS rows 128B (64 f16: hi 0-31 | lo 32-63), T2 swizzle slot ^= (row&7).
//  - B from PRE-SWIZZLED global chunks (linear GLD16 + swizzled read).
//  - A (x fp32) reg-staged: load -> scale/split -> swizzled ds_write.
//  - B tri-buffered (prefetch distance 2), A reg distance 2 (named sets,
//    pair-unrolled). ONE barrier + ONE counted vmcnt(6) per K-step.
//  - setprio(1) around the 48-MFMA cluster.
// ---------------------------------------------------------------------------
__global__ __launch_bounds__(512, 2)
void gemm_g1(const float* __restrict__ x, const _Float16* __restrict__ w1S,
             float* __restrict__ partOut)
{
    __shared__ _Float16 Asw[2][256 * 64];
    __shared__ _Float16 Bsw[3][128 * 64];

    const int tid  = threadIdx.x;
    const int lane = tid & 63;
    const int wave = tid >> 6;
    const int wm = wave >> 2, wn = wave & 3;
    const int l15 = lane & 15;
    const int quad = lane >> 4;

    // b = bn*64 + ks*32 + bm: bn-peers of one (bm,ks) share b%8 (same XCD).
    const int b  = blockIdx.x;
    const int bm = b & 31;
    const int ks = (b >> 5) & 1;
    const int bn = b >> 6;
    const int row0 = bm * 256;
    const int col0 = bn * 128;
    const int k0   = ks * 2048;          // Kslice = 2048, Ksteps = 64

    const int ar = tid >> 1, kh = tid & 1, arx = ar & 7;
    const float* aBase = x + (size_t)(row0 + ar) * FEAT + k0 + kh * 16;

    const int aw0 = ar * 64 + (((2 * kh)     ^ arx) * 8);
    const int aw1 = ar * 64 + (((2 * kh + 1) ^ arx) * 8);
    const int aw2 = ar * 64 + (((4 + 2 * kh) ^ arx) * 8);
    const int aw3 = ar * 64 + (((5 + 2 * kh) ^ arx) * 8);

    const _Float16* bBase = w1S + (size_t)(bn * 128 + ks * 64) * 8192 + tid * 8;

    floatx4 acc[8][2] = {};
    float4 fE0, fE1, fE2, fE3, fO0, fO1, fO2, fO3;

#define LOADA(t, g0, g1, g2, g3)                                               \
    do {                                                                       \
        const float4* p_ = (const float4*)(aBase + (t) * 32);                  \
        g0 = p_[0]; g1 = p_[1]; g2 = p_[2]; g3 = p_[3];                        \
    } while (0)

#define STAGEB(t, buf)                                                         \
    do {                                                                       \
        const _Float16* g_ = bBase + (size_t)(t) * 8192;                       \
        GLD16(g_,        &Bsw[buf][tid * 8]);                                  \
        GLD16(g_ + 4096, &Bsw[buf][4096 + tid * 8]);                           \
    } while (0)

#define CVTSTORE(buf, g0, g1, g2, g3)                                          \
    do {                                                                       \
        float fv[16] = {g0.x,g0.y,g0.z,g0.w, g1.x,g1.y,g1.z,g1.w,              \
                        g2.x,g2.y,g2.z,g2.w, g3.x,g3.y,g3.z,g3.w};             \
        half8 hv0, hv1, lv0, lv1;                                              \
        _Pragma("unroll")                                                      \
        for (int e = 0; e < 8; ++e) {                                          \
            float v = fv[e] * SC_X;                                            \
            _Float16 h = (_Float16)v;                                          \
            hv0[e] = h; lv0[e] = (_Float16)(v - (float)h);                     \
        }                                                                      \
        _Pragma("unroll")                                                      \
        for (int e = 0; e < 8; ++e) {                                          \
            float v = fv[8 + e] * SC_X;                                        \
            _Float16 h = (_Float16)v;                                          \
            hv1[e] = h; lv1[e] = (_Float16)(v - (float)h);                     \
        }                                                                      \
        *(half8*)&Asw[buf][aw0] = hv0;                                         \
        *(half8*)&Asw[buf][aw1] = hv1;                                         \
        *(half8*)&Asw[buf][aw2] = lv0;                                         \
        *(half8*)&Asw[buf][aw3] = lv1;                                         \
    } while (0)

#define COMPUTE(ab, rb_)                                                       \
    do {                                                                       \
        half8 bhf[2], blf[2];                                                  \
        _Pragma("unroll")                                                      \
        for (int j = 0; j < 2; ++j) {                                          \
            int r_ = wn * 32 + j * 16 + l15;                                   \
            int bs_ = r_ * 64;                                                 \
            bhf[j] = *(const half8*)&Bsw[rb_][bs_ + ((quad ^ (r_ & 7)) * 8)];  \
            blf[j] = *(const half8*)&Bsw[rb_][bs_ + (((4 + quad) ^ (r_ & 7)) * 8)]; \
        }                                                                      \
        __builtin_amdgcn_s_setprio(1);                                         \
        _Pragma("unroll")                                                      \
        for (int i = 0; i < 8; ++i) {                                          \
            int r_ = wm * 128 + i * 16 + l15;                                  \
            int as_ = r_ * 64;                                                 \
            half8 ah = *(const half8*)&Asw[ab][as_ + ((quad ^ (r_ & 7)) * 8)]; \
            half8 al = *(const half8*)&Asw[ab][as_ + (((4 + quad) ^ (r_ & 7)) * 8)]; \
            _Pragma("unroll")                                                  \
            for (int j = 0; j < 2; ++j) {                                      \
                acc[i][j] = __builtin_amdgcn_mfma_f32_16x16x32_f16(ah, bhf[j], acc[i][j], 0, 0, 0); \
                acc[i][j] = __builtin_amdgcn_mfma_f32_16x16x32_f16(ah, blf[j], acc[i][j], 0, 0, 0); \
                acc[i][j] = __builtin_amdgcn_mfma_f32_16x16x32_f16(al, bhf[j], acc[i][j], 0, 0, 0); \
            }                                                                  \
        }                                                                      \
        __builtin_amdgcn_s_setprio(0);                                         \
    } while (0)

    // ---- prologue ----
    LOADA(0, fE0, fE1, fE2, fE3);
    STAGEB(0, 0);
    STAGEB(1, 1);
    LOADA(1, fO0, fO1, fO2, fO3);
    asm volatile("s_waitcnt vmcnt(6)" ::: "memory");  // retires A(0)x4 + B(0)x2
    CVTSTORE(0, fE0, fE1, fE2, fE3);
    asm volatile("s_waitcnt lgkmcnt(0)" ::: "memory");
    __builtin_amdgcn_sched_barrier(0);
    __builtin_amdgcn_s_barrier();

    int rb = 0;
    for (int t = 0; t < 64; t += 2) {
        {   // even step t: reads Asw[0]/Bsw[rb]
            int sb = rb + 2; if (sb >= 3) sb -= 3;
            if (t + 2 < 64) { STAGEB(t + 2, sb); LOADA(t + 2, fE0, fE1, fE2, fE3); }
            COMPUTE(0, rb);
            if (t + 2 < 64) asm volatile("s_waitcnt vmcnt(6)" ::: "memory");
            else            asm volatile("s_waitcnt vmcnt(0)" ::: "memory");
            CVTSTORE(1, fO0, fO1, fO2, fO3);   // A(t+1) -> Asw[1]
            asm volatile("s_waitcnt lgkmcnt(0)" ::: "memory");
            __builtin_amdgcn_sched_barrier(0);
            __builtin_amdgcn_s_barrier();
            rb = rb + 1; if (rb >= 3) rb -= 3;
        }
        {   // odd step t+1: reads Asw[1]/Bsw[rb]
            int sb = rb + 2; if (sb >= 3) sb -= 3;
            if (t + 3 < 64) { STAGEB(t + 3, sb); LOADA(t + 3, fO0, fO1, fO2, fO3); }
            COMPUTE(1, rb);
            if (t + 2 < 64) {
                if (t + 3 < 64) asm volatile("s_waitcnt vmcnt(6)" ::: "memory");
                else            asm volatile("s_waitcnt vmcnt(0)" ::: "memory");
                CVTSTORE(0, fE0, fE1, fE2, fE3);   // A(t+2) -> Asw[0]
                asm volatile("s_waitcnt lgkmcnt(0)" ::: "memory");
            }
            __builtin_amdgcn_sched_barrier(0);
            __builtin_amdgcn_s_barrier();
            rb = rb + 1; if (rb >= 3) rb -= 3;
        }
    }

    // Epilogue: raw fp32 partials. C/D layout: col=lane&15, row=quad*4+reg.
    float* po = partOut + (size_t)ks * BATCH * MID;
    #pragma unroll
    for (int j = 0; j < 2; ++j) {
        int col = col0 + wn * 32 + j * 16 + l15;
        #pragma unroll
        for (int i = 0; i < 8; ++i)
            #pragma unroll
            for (int tt = 0; tt < 4; ++tt) {
                int r = row0 + wm * 128 + i * 16 + quad * 4 + tt;
                po[(size_t)r * MID + col] = acc[i][j][tt];
            }
    }
#undef LOADA
#undef STAGEB
#undef CVTSTORE
#undef COMPUTE
}

// ---------------------------------------------------------------------------
// Split-K MFMA GEMM, 128x128 tile, BK=32, 4 waves (2x2 of 64x64).
// Used for G2/G3/decoder. NT=3: 3-term hi/lo. ASRC=0 GLD16 planes,
// ASRC=1 fp32 reg-split, ASRC=2 fused split-K reduce (h = relu((s0+s1)*ds+b)).
// Counted-vmcnt schedule, raw barriers (see round-3 notes).
// ---------------------------------------------------------------------------
template<int NT, int ASRC>
__global__ __launch_bounds__(256)
void gemm_sk(const float* __restrict__ Af32,
             const _Float16* __restrict__ Ahg, const _Float16* __restrict__ Alg,
             const _Float16* __restrict__ BTh, const _Float16* __restrict__ BTl,
             float aScale,
             const float* __restrict__ redBias, float redDS, int redMN,
             float* __restrict__ partOut,
             const float* __restrict__ bias, float descale, int relu,
             float* __restrict__ outF, _Float16* __restrict__ outHi,
             _Float16* __restrict__ outLo, float outScale,
             int M, int N, int K, int lgK, int lgN, int swz)
{
    __shared__ _Float16 AhS[2][128 * 32];
    __shared__ _Float16 BhS[2][128 * 32];
    __shared__ _Float16 AlS[NT == 3 ? 2 : 1][NT == 3 ? 128 * 32 : 8];
    __shared__ _Float16 BlS[NT == 3 ? 2 : 1][NT == 3 ? 128 * 32 : 8];

    const int tid  = threadIdx.x;
    const int lane = tid & 63;
    const int wave = tid >> 6;
    const int wm = wave >> 1, wn = wave & 1;
    const int l15  = lane & 15;
    const int quad = lane >> 4;
    const int q8   = quad * 8;

    int bm, bn, ks;
    if (swz) {
        int bb = blockIdx.x;
        int mlo = bb & 7;
        ks = (bb >> 3) & ((1 << lgK) - 1);
        bn = (bb >> (3 + lgK)) & ((1 << lgN) - 1);
        bm = ((bb >> (3 + lgK + lgN)) << 3) | mlo;
    } else { bm = blockIdx.y; bn = blockIdx.x; ks = 0; }
    const int row0 = bm * 128, col0 = bn * 128;
    const int Kslice = K >> lgK;
    const int k0 = ks * Kslice;

    const int sr4 = tid >> 2;
    const int sc4 = (tid & 3) * 8;
    const size_t aB0 = (size_t)(row0 + sr4) * K + sc4;
    const size_t aB1 = (size_t)(row0 + 64 + sr4) * K + sc4;
    const size_t bB0 = (size_t)(col0 + sr4) * K + sc4;
    const size_t bB1 = (size_t)(col0 + 64 + sr4) * K + sc4;
    const int l0 = tid * 8, l1 = 2048 + tid * 8;

    const int sr2 = tid >> 1;
    const int sk2 = (tid & 1) * 16;
    const size_t aOff2 = (size_t)(row0 + sr2) * K + sk2;
    const int lA = sr2 * 32 + sk2;

    floatx4 acc[4][4] = {};

    auto cvtA1 = [&](int s, float4 f0, float4 f1, float4 f2, float4 f3) {
        float fv[16] = {f0.x,f0.y,f0.z,f0.w, f1.x,f1.y,f1.z,f1.w,
                        f2.x,f2.y,f2.z,f2.w, f3.x,f3.y,f3.z,f3.w};
        half8 hv0, hv1, lv0, lv1;
        #pragma unroll
        for (int e = 0; e < 8; ++e) {
            float v = fv[e] * aScale;
            _Float16 h = (_Float16)v;
            hv0[e] = h; lv0[e] = (_Float16)(v - (float)h);
        }
        #pragma unroll
        for (int e = 0; e < 8; ++e) {
            float v = fv[8 + e] * aScale;
            _Float16 h = (_Float16)v;
            hv1[e] = h; lv1[e] = (_Float16)(v - (float)h);
        }
        *(half8*)&AhS[s][lA] = hv0; *(half8*)&AhS[s][lA + 8] = hv1;
        if (NT == 3) {
            *(half8*)&AlS[s][lA] = lv0; *(half8*)&AlS[s][lA + 8] = lv1;
        }
    };

    auto cvtA2 = [&](int s,
                     float4 A0, float4 A1, float4 A2, float4 A3,
                     float4 C0, float4 C1, float4 C2, float4 C3,
                     float4 B0, float4 B1, float4 B2, float4 B3) {
        float sv[16] = {A0.x+C0.x, A0.y+C0.y, A0.z+C0.z, A0.w+C0.w,
                        A1.x+C1.x, A1.y+C1.y, A1.z+C1.z, A1.w+C1.w,
                        A2.x+C2.x, A2.y+C2.y, A2.z+C2.z, A2.w+C2.w,
                        A3.x+C3.x, A3.y+C3.y, A3.z+C3.z, A3.w+C3.w};
        float bv[16] = {B0.x,B0.y,B0.z,B0.w, B1.x,B1.y,B1.z,B1.w,
                        B2.x,B2.y,B2.z,B2.w, B3.x,B3.y,B3.z,B3.w};
        half8 hv0, hv1, lv0, lv1;
        #pragma unroll
        for (int e = 0; e < 8; ++e) {
            float t = sv[e] * redDS + bv[e];
            t = fmaxf(t, 0.0f);
            float v = t * aScale;
            _Float16 h = (_Float16)v;
            hv0[e] = h; lv0[e] = (_Float16)(v - (float)h);
        }
        #pragma unroll
        for (int e = 0; e < 8; ++e) {
            float t = sv[8 + e] * redDS + bv[8 + e];
            t = fmaxf(t, 0.0f);
            float v = t * aScale;
            _Float16 h = (_Float16)v;
            hv1[e] = h; lv1[e] = (_Float16)(v - (float)h);
        }
        *(half8*)&AhS[s][lA] = hv0; *(half8*)&AhS[s][lA + 8] = hv1;
        *(half8*)&AlS[s][lA] = lv0; *(half8*)&AlS[s][lA + 8] = lv1;
    };

    const int Ksteps = Kslice >> 5;
    constexpr int PFW = (ASRC == 2) ? 16 : (NT == 3 ? 8 : (ASRC == 1 ? 6 : 4));

    {
        if constexpr (ASRC == 0) {
            GLD16(Ahg + aB0 + k0, &AhS[0][l0]);
            GLD16(Ahg + aB1 + k0, &AhS[0][l1]);
            if (NT == 3) {
                GLD16(Alg + aB0 + k0, &AlS[0][l0]);
                GLD16(Alg + aB1 + k0, &AlS[0][l1]);
            }
        }
        GLD16(BTh + bB0 + k0, &BhS[0][l0]);
        GLD16(BTh + bB1 + k0, &BhS[0][l1]);
        if (NT == 3) {
            GLD16(BTl + bB0 + k0, &BlS[0][l0]);
            GLD16(BTl + bB1 + k0, &BlS[0][l1]);
        }
        if constexpr (ASRC == 1) {
            const float* p = Af32 + aOff2 + k0;
            float4 f0 = *(const float4*)(p);
            float4 f1 = *(const float4*)(p + 4);
            float4 f2 = *(const float4*)(p + 8);
            float4 f3 = *(const float4*)(p + 12);
            cvtA1(0, f0, f1, f2, f3);
            asm volatile("s_waitcnt lgkmcnt(0)" ::: "memory");
        } else if constexpr (ASRC == 2) {
            const float* p0 = Af32 + aOff2 + k0;
            const float* p1 = p0 + redMN;
            const float* pb = redBias + k0 + sk2;
            float4 A0 = ((const float4*)p0)[0], A1 = ((const float4*)p0)[1];
            float4 A2 = ((const float4*)p0)[2], A3 = ((const float4*)p0)[3];
            float4 C0 = ((const float4*)p1)[0], C1 = ((const float4*)p1)[1];
            float4 C2 = ((const float4*)p1)[2], C3 = ((const float4*)p1)[3];
            float4 B0 = ((const float4*)pb)[0], B1 = ((const float4*)pb)[1];
            float4 B2 = ((const float4*)pb)[2], B3 = ((const float4*)pb)[3];
            cvtA2(0, A0,A1,A2,A3, C0,C1,C2,C3, B0,B1,B2,B3);
            asm volatile("s_waitcnt lgkmcnt(0)" ::: "memory");
        }
    }

    for (int it = 0; it < Ksteps; ++it) {
        const int cur = it & 1, nxt = cur ^ 1;
        const bool pf = (it + 1) < Ksteps;
        float4 f0, f1, f2, f3;
        float4 A0, A1, A2, A3, C0, C1, C2, C3, B0, B1, B2, B3;
        if (pf) {
            const int kk = k0 + (it + 1) * 32;
            if constexpr (ASRC == 0) {
                GLD16(Ahg + aB0 + kk, &AhS[nxt][l0]);
                GLD16(Ahg + aB1 + kk, &AhS[nxt][l1]);
                if (NT == 3) {
                    GLD16(Alg + aB0 + kk, &AlS[nxt][l0]);
                    GLD16(Alg + aB1 + kk, &AlS[nxt][l1]);
                }
            } else if constexpr (ASRC == 1) {
                const float* p = Af32 + aOff2 + kk;
                f0 = *(const float4*)(p);
                f1 = *(const float4*)(p + 4);
                f2 = *(const float4*)(p + 8);
                f3 = *(const float4*)(p + 12);
            } else {
                const float* p0 = Af32 + aOff2 + kk;
                const float* p1 = p0 + redMN;
                const float* pb = redBias + kk + sk2;
                A0 = ((const float4*)p0)[0]; A1 = ((const float4*)p0)[1];
                A2 = ((const float4*)p0)[2]; A3 = ((const float4*)p0)[3];
                C0 = ((const float4*)p1)[0]; C1 = ((const float4*)p1)[1];
                C2 = ((const float4*)p1)[2]; C3 = ((const float4*)p1)[3];
                B0 = ((const float4*)pb)[0]; B1 = ((const float4*)pb)[1];
                B2 = ((const float4*)pb)[2]; B3 = ((const float4*)pb)[3];
            }
            GLD16(BTh + bB0 + kk, &BhS[nxt][l0]);
            GLD16(BTh + bB1 + kk, &BhS[nxt][l1]);
            if (NT == 3) {
                GLD16(BTl + bB0 + kk, &BlS[nxt][l0]);
                GLD16(BTl + bB1 + kk, &BlS[nxt][l1]);
            }
            asm volatile("s_waitcnt vmcnt(%0)" :: "i"(PFW) : "memory");
        } else {
            asm volatile("s_waitcnt vmcnt(0)" ::: "memory");
        }
        __builtin_amdgcn_s_barrier();

        half8 ah[4], al4[4], bh[4], bl4[4];
        #pragma unroll
        for (int i = 0; i < 4; ++i) {
            int ra = (wm * 64 + i * 16 + l15) * 32 + q8;
            int rbx = (wn * 64 + i * 16 + l15) * 32 + q8;
            ah[i] = *(const half8*)&AhS[cur][ra];
            bh[i] = *(const half8*)&BhS[cur][rbx];
            if (NT == 3) {
                al4[i] = *(const half8*)&AlS[cur][ra];
                bl4[i] = *(const half8*)&BlS[cur][rbx];
            }
        }
        #pragma unroll
        for (int i = 0; i < 4; ++i)
            #pragma unroll
            for (int j = 0; j < 4; ++j) {
                acc[i][j] = __builtin_amdgcn_mfma_f32_16x16x32_f16(ah[i], bh[j], acc[i][j], 0, 0, 0);
                if (NT == 3) {
                    acc[i][j] = __builtin_amdgcn_mfma_f32_16x16x32_f16(ah[i],  bl4[j], acc[i][j], 0, 0, 0);
                    acc[i][j] = __builtin_amdgcn_mfma_f32_16x16x32_f16(al4[i], bh[j],  acc[i][j], 0, 0, 0);
                }
            }
        if constexpr (ASRC == 1) {
            if (pf) {
                cvtA1(nxt, f0, f1, f2, f3);
                asm volatile("s_waitcnt lgkmcnt(0)" ::: "memory");
            }
        } else if constexpr (ASRC == 2) {
            if (pf) {
                cvtA2(nxt, A0,A1,A2,A3, C0,C1,C2,C3, B0,B1,B2,B3);
                asm volatile("s_waitcnt lgkmcnt(0)" ::: "memory");
            }
        }
        __builtin_amdgcn_s_barrier();
    }

    if (partOut) {
        float* po = partOut + (size_t)ks * M * N;
        #pragma unroll
        for (int j = 0; j < 4; ++j) {
            int col = col0 + wn * 64 + j * 16 + l15;
            #pragma unroll
            for (int i = 0; i < 4; ++i)
                #pragma unroll
                for (int t = 0; t < 4; ++t) {
                    int r = row0 + wm * 64 + i * 16 + quad * 4 + t;
                    po[(size_t)r * N + col] = acc[i][j][t];
                }
        }
    } else {
        #pragma unroll
        for (int j = 0; j < 4; ++j) {
            int col = col0 + wn * 64 + j * 16 + l15;
            float bcol = bias ? bias[col] : 0.0f;
            #pragma unroll
            for (int i = 0; i < 4; ++i)
                #pragma unroll
                for (int t = 0; t < 4; ++t) {
                    int r = row0 + wm * 64 + i * 16 + quad * 4 + t;
                    float v = acc[i][j][t] * descale + bcol;
                    if (relu) v = fmaxf(v, 0.0f);
                    size_t o = (size_t)r * N + col;
                    if (outF) outF[o] = v;
                    if (outHi) {
                        float sv = v * outScale;
                        _Float16 h = (_Float16)sv;
                        outHi[o] = h;
                        outLo[o] = (_Float16)(sv - (float)h);
                    }
                }
        }
    }
}

// ---------------------------------------------------------------------------
__global__ __launch_bounds__(256)
void reduce_sk(const float* __restrict__ part, int nSlice, int MN, int N,
               const float* __restrict__ bias, float descale, int relu,
               float* __restrict__ outF, _Float16* __restrict__ outHi,
               _Float16* __restrict__ outLo, float outScale)
{
    int i = blockIdx.x * 256 + threadIdx.x;
    if (i * 4 >= MN) return;
    float4 s = ((const float4*)part)[i];
    for (int sl = 1; sl < nSlice; ++sl) {
        float4 p = ((const float4*)(part + (size_t)sl * MN))[i];
        s.x += p.x; s.y += p.y; s.z += p.z; s.w += p.w;
    }
    int col = (i * 4) % N;
    float v[4] = {s.x, s.y, s.z, s.w};
    #pragma unroll
    for (int e = 0; e < 4; ++e) {
        float t = v[e] * descale + (bias ? bias[col + e] : 0.0f);
        if (relu) t = fmaxf(t, 0.0f);
        v[e] = t;
    }
    if (outF) ((float4*)outF)[i] = *(float4*)v;
    if (outHi) {
        half4v hv, lv;
        #pragma unroll
        for (int e = 0; e < 4; ++e) {
            float sv = v[e] * outScale;
            _Float16 h = (_Float16)sv;
            hv[e] = h;
            lv[e] = (_Float16)(sv - (float)h);
        }
        ((half4v*)outHi)[i] = hv;
        ((half4v*)outLo)[i] = lv;
    }
}

// ---------------------------------------------------------------------------
__device__ __forceinline__ void transpose_body(
    float (*t)[33],
    const float* __restrict__ src, _Float16* __restrict__ hi,
    _Float16* __restrict__ lo, float scale, int R, int C, int bx, int by)
{
    int tx = threadIdx.x & 31, ty = threadIdx.x >> 5;
    int r0 = by * 32, c0 = bx * 32;
    #pragma unroll
    for (int p = 0; p < 4; ++p) {
        int r = ty + p * 8;
        t[r][tx] = src[(size_t)(r0 + r) * C + c0 + tx];
    }
    __syncthreads();
    #pragma unroll
    for (int p = 0; p < 4; ++p) {
        int oc = ty + p * 8;
        float v = t[tx][oc] * scale;
        _Float16 h = (_Float16)v;
        size_t o = (size_t)(c0 + oc) * R + r0 + tx;
        hi[o] = h;
        lo[o] = (_Float16)(v - (float)h);
    }
}

// ---------------------------------------------------------------------------
// All prep in ONE launch. enc_w1 goes to SWIZZLED chunks for gemm_g1:
// chunk = (n>>7)*128 + (k>>5); within: 128 rows x 64 f16 (hi slots 0-3 |
// lo slots 4-7), 16B-slot ^= (row&7).
// ---------------------------------------------------------------------------
__global__ __launch_bounds__(256)
void prep_fused(const float* __restrict__ enc_w1, const float* __restrict__ enc_w2,
                const float* __restrict__ dec_w1, const float* __restrict__ dec_w2,
                const float* __restrict__ emb,
                _Float16* __restrict__ w1S,
                _Float16* __restrict__ w2T_hi, _Float16* __restrict__ w2T_lo,
                _Float16* __restrict__ wd1T_hi, _Float16* __restrict__ wd1T_lo,
                _Float16* __restrict__ wd2T_hi, _Float16* __restrict__ wd2T_lo,
                _Float16* __restrict__ cnHi, _Float16* __restrict__ cnLo,
                float* __restrict__ out_emb)
{
    __shared__ float t[32][33];
    const int b = blockIdx.x;
    if (b < 2048) {
        int bx = b & 15, by = b >> 4;
        int tx = threadIdx.x & 31, ty = threadIdx.x >> 5;
        int r0 = by * 32, c0 = bx * 32;       // r: FEAT(k), c: MID(n)
        #pragma unroll
        for (int p = 0; p < 4; ++p) {
            int r = ty + p * 8;
            t[r][tx] = enc_w1[(size_t)(r0 + r) * MID + c0 + tx];
        }
        __syncthreads();
        #pragma unroll
        for (int p = 0; p < 4; ++p) {
            int oc = ty + p * 8;
            float v = t[tx][oc] * SC_W;
            _Float16 h = (_Float16)v;
            _Float16 l = (_Float16)(v - (float)h);
            int n = c0 + oc, k = r0 + tx;
            int nt = n >> 7, rr = n & 127, kc = k & 31;
            size_t chunk = (size_t)(nt * 128 + (k >> 5)) * 8192;
            int rx = rr & 7, q = kc >> 3, fb = kc & 7;
            w1S[chunk + rr * 64 + ((q ^ rx) * 8) + fb]       = h;
            w1S[chunk + rr * 64 + (((4 + q) ^ rx) * 8) + fb] = l;
        }
    } else if (b < 2176) {
        int bb = b - 2048;
        transpose_body(t, enc_w2, w2T_hi, w2T_lo, SC_W, MID, EMB, bb & 7, bb >> 3);
    } else if (b < 2304) {
        int bb = b - 2176;
        transpose_body(t, dec_w1, wd1T_hi, wd1T_lo, SC_W, EMB, MID, bb & 15, bb >> 4);
    } else if (b < 4352) {
        int bb = b - 2304;
        transpose_body(t, dec_w2, wd2T_hi, wd2T_lo, SC_W, MID, FEAT, bb & 127, bb >> 7);
    } else if (b < 4480) {
        int wv = threadIdx.x >> 6, lane = threadIdx.x & 63;
        int c = (b - 4352) * 4 + wv;
        const float* er = emb + (size_t)c * EMB;
        float ss = 0.0f;
        #pragma unroll
        for (int k = lane; k < EMB; k += 64) { float v = er[k]; ss += v * v; }
        #pragma unroll
        for (int off = 32; off > 0; off >>= 1) ss += __shfl_down(ss, off, 64);
        ss = __shfl(ss, 0, 64);
        float inv = 1.0f / (sqrtf(ss) + 1e-12f);
        #pragma unroll
        for (int k = lane; k < EMB; k += 64) {
            float v = er[k] * inv * SC_CODE;
            _Float16 h = (_Float16)v;
            cnHi[(size_t)c * EMB + k] = h;
            cnLo[(size_t)c * EMB + k] = (_Float16)(v - (float)h);
        }
    } else {
        int i = (b - 4480) * 256 + threadIdx.x;
        ((float4*)out_emb)[i] = ((const float4*)emb)[i];
    }
}

// ---------------------------------------------------------------------------
__global__ __launch_bounds__(256)
void argmax_vq3(const float* __restrict__ part, int MN,
                const float* __restrict__ emb,
                const float* __restrict__ Dcode,
                float* __restrict__ onehot, float* __restrict__ vqfeat,
                float* __restrict__ decoded)
{
    __shared__ int sBest;
    const int row = blockIdx.x;
    const int tid = threadIdx.x;

    if (tid < 64) {
        const float* p0 = part + (size_t)row * KCODE;
        const float* p1 = part + (size_t)MN + (size_t)row * KCODE;
        float bestV = -3.402823466e+38f;
        int   bestI = 0;
        #pragma unroll
        for (int c = tid; c < KCODE; c += 64) {
            float v = p0[c] + p1[c];
            if (v > bestV) { bestV = v; bestI = c; }
        }
        #pragma unroll
        for (int off = 32; off > 0; off >>= 1) {
            float ov = __shfl_down(bestV, off, 64);
            int   oi = __shfl_down(bestI, off, 64);
            if (ov > bestV || (ov == bestV && oi < bestI)) { bestV = ov; bestI = oi; }
        }
        if (tid == 0) sBest = bestI;
    }
    __syncthreads();
    const int bestI = sBest;

    float* oh = onehot + (size_t)row * KCODE;
    oh[tid]       = (tid       == bestI) ? 1.0f : 0.0f;
    oh[tid + 256] = (tid + 256 == bestI) ? 1.0f : 0.0f;

    vqfeat[(size_t)row * EMB + tid] = emb[(size_t)bestI * EMB + tid];

    const float4* sd = (const float4*)(Dcode + (size_t)bestI * FEAT);
    float4* dd = (float4*)(decoded + (size_t)row * FEAT);
    #pragma unroll
    for (int i = tid; i < FEAT / 4; i += 256) dd[i] = sd[i];
}

// ---------------------------------------------------------------------------
extern "C" void kernel_launch(void* const* d_in, const int* in_sizes, int n_in,
                              void* d_out, int out_size, void* d_ws, size_t ws_size,
                              hipStream_t stream)
{
    const float* x      = (const float*)d_in[0];
    const float* enc_w1 = (const float*)d_in[1];
    const float* enc_b1 = (const float*)d_in[2];
    const float* enc_w2 = (const float*)d_in[3];
    const float* enc_b2 = (const float*)d_in[4];
    const float* emb    = (const float*)d_in[5];
    const float* dec_w1 = (const float*)d_in[6];
    const float* dec_b1 = (const float*)d_in[7];
    const float* dec_w2 = (const float*)d_in[8];
    const float* dec_b2 = (const float*)d_in[9];

    float* out = (float*)d_out;
    float* out_encoded = out;
    float* out_vqfeat  = out + (size_t)BATCH * EMB;
    float* out_onehot  = out + (size_t)2 * BATCH * EMB;
    float* out_decoded = out + (size_t)2 * BATCH * EMB + (size_t)BATCH * KCODE;
    float* out_emb     = out_decoded + (size_t)BATCH * FEAT;

    char* w = (char*)d_ws;
    _Float16* w1S    = (_Float16*)w;  w += (size_t)FEAT * MID * 2 * 2;  // 8MB
    _Float16* w2T_hi = (_Float16*)w;  w += (size_t)MID * EMB * 2;
    _Float16* w2T_lo = (_Float16*)w;  w += (size_t)MID * EMB * 2;
    _Float16* wd1T_hi= (_Float16*)w;  w += (size_t)MID * EMB * 2;
    _Float16* wd1T_lo= (_Float16*)w;  w += (size_t)MID * EMB * 2;
    _Float16* wd2T_hi= (_Float16*)w;  w += (size_t)FEAT * MID * 2;
    _Float16* wd2T_lo= (_Float16*)w;  w += (size_t)FEAT * MID * 2;
    _Float16* enc_hi = (_Float16*)w;  w += (size_t)BATCH * EMB * 2;
    _Float16* enc_lo = (_Float16*)w;  w += (size_t)BATCH * EMB * 2;
    _Float16* cn_hi  = (_Float16*)w;  w += (size_t)KCODE * EMB * 2;
    _Float16* cn_lo  = (_Float16*)w;  w += (size_t)KCODE * EMB * 2;
    _Float16* tm_hi  = (_Float16*)w;  w += (size_t)KCODE * MID * 2;
    _Float16* tm_lo  = (_Float16*)w;  w += (size_t)KCODE * MID * 2;
    float*    Dc     = (float*)w;     w += (size_t)KCODE * FEAT * 4;
    float*    scr    = (float*)w;     w += (size_t)4 * BATCH * MID * 4;
    float*    scr2   = scr + (size_t)2 * BATCH * MID;

    prep_fused<<<dim3(4608), dim3(256), 0, stream>>>(
        enc_w1, enc_w2, dec_w1, dec_w2, emb,
        w1S, w2T_hi, w2T_lo, wd1T_hi, wd1T_lo, wd2T_hi, wd2T_lo,
        cn_hi, cn_lo, out_emb);

    gemm_sk<1, 1><<<dim3(KCODE / 128, KCODE / 128), dim3(256), 0, stream>>>(
        emb, nullptr, nullptr, wd1T_hi, wd1T_lo, SC_EMB,
        nullptr, 0.0f, 0,
        nullptr, dec_b1, DS_D1, 1, nullptr, tm_hi, tm_lo, SC_TM,
        KCODE, MID, EMB, 0, 0, 0);
    gemm_sk<1, 0><<<dim3(FEAT / 128, KCODE / 128), dim3(256), 0, stream>>>(
        nullptr, tm_hi, tm_lo, wd2T_hi, wd2T_lo, 0.0f,
        nullptr, 0.0f, 0,
        nullptr, dec_b2, DS_D2, 1, Dc, nullptr, nullptr, 0.0f,
        KCODE, FEAT, MID, 0, 0, 0);

    // --- G1: dedicated 256x128 8-wave T2-swizzled kernel; split-K=2 ---
    gemm_g1<<<dim3(256), dim3(512), 0, stream>>>(x, w1S, scr);

    // --- G2: h @ w2; A-staging fuses red1 ---
    gemm_sk<3, 2><<<dim3(512), dim3(256), 0, stream>>>(
        scr, nullptr, nullptr, w2T_hi, w2T_lo, SC_H,
        enc_b1, DS_G1, BATCH * MID,
        scr2, nullptr, 0.0f, 0, nullptr, nullptr, nullptr, 0.0f,
        BATCH, EMB, MID, 2, 1, 1);
    reduce_sk<<<dim3(BATCH * EMB / 4 / 256), dim3(256), 0, stream>>>(
        scr2, 4, BATCH * EMB, EMB, enc_b2, DS_G2, 0,
        out_encoded, enc_hi, enc_lo, SC_ENC);

    // --- G3: enc @ cn^T ---
    gemm_sk<3, 0><<<dim3(512), dim3(256), 0, stream>>>(
        nullptr, enc_hi, enc_lo, cn_hi, cn_lo, 0.0f,
        nullptr, 0.0f, 0,
        scr, nullptr, 0.0f, 0, nullptr, nullptr, nullptr, 0.0f,
        BATCH, KCODE, EMB, 1, 2, 1);
    argmax_vq3<<<dim3(BATCH), dim3(256), 0, stream>>>(
        scr, BATCH * KCODE, emb, Dc, out_onehot, out_vqfeat, out_decoded);
}